// Round 6
// baseline (1444.964 us; speedup 1.0000x reference)
//
#include <hip/hip_runtime.h>
#include <stdint.h>

// Problem constants
#define NB    16
#define NN    4096
#define NP    1024
#define NS    32
#define NGRP  (NB*NP)          // 16384 groups
#define CNT   524288.0         // B*K*S elements per channel for BN stats
#define NWRK  240              // worker blocks (grid 256 = 16 FPS + 240)
#define TGRID 1024             // tail kernel grid (4 blocks/CU x 256 CU, exact capacity)

typedef short  bf16x8 __attribute__((ext_vector_type(8)));
typedef float  f32x4  __attribute__((ext_vector_type(4)));

// ---------- bf16 helpers (RNE) ----------
__device__ __forceinline__ float bf2f(unsigned short u) {
    return __uint_as_float(((unsigned)u) << 16);
}
__device__ __forceinline__ unsigned short f2bf(float f) {
    unsigned u = __float_as_uint(f);
    unsigned r = u + 0x7fffu + ((u >> 16) & 1u);
    return (unsigned short)(r >> 16);
}
__device__ __forceinline__ bf16x8 as_bf(uint4 u) {
    union { uint4 a; bf16x8 b; } c; c.a = u; return c.b;
}

// u64 max with one DPP step (compare-select). VALU-only.
template <int CTRL, int RM>
__device__ __forceinline__ unsigned long long dppmax(unsigned long long k) {
    int lo = (int)(unsigned)k;
    int hi = (int)(k >> 32);
    int ml = __builtin_amdgcn_update_dpp(lo, lo, CTRL, RM, 0xf, false);
    int mh = __builtin_amdgcn_update_dpp(hi, hi, CTRL, RM, 0xf, false);
    unsigned long long m = ((unsigned long long)(unsigned)mh << 32) | (unsigned)ml;
    return m > k ? m : k;
}

// =====================================================================
// FUSED K1 (r5, measured 636us): blocks 0..15 FPS w/ chunked publish;
// blocks 16..255 workers: T transform -> barrier -> s-major group quads.
// =====================================================================
__global__ __launch_bounds__(256, 1) void fused_kernel(const float* __restrict__ xyz,
                                                       const float* __restrict__ points,
                                                       const float* __restrict__ w0,
                                                       const float* __restrict__ b0,
                                                       int* __restrict__ fidx,
                                                       unsigned short* __restrict__ T,
                                                       int* __restrict__ idx,
                                                       double* __restrict__ stage1,
                                                       float* __restrict__ out0,
                                                       int* __restrict__ sync_ctr) {
    __shared__ float4 sxyz4[NN];                    // 64 KB (FPS centroid cache)
    __shared__ unsigned long long red[2][4];        // FPS: parity x wave slots
    __shared__ int fbuf[NP];                        // FPS: result staging (LDS)
    __shared__ int gidx[4][NS];                     // group: per-wave ball idx
    int tid = threadIdx.x;
    int wv = tid >> 6, lane = tid & 63;

    if (blockIdx.x < 16) {
        // ---------------- FPS path (round-0 body + chunked publish) ----
        int b = blockIdx.x;
        const float* xb = xyz + (size_t)b * 3 * NN;
        float px[16], py[16], pz[16], dist[16];
#pragma unroll
        for (int i = 0; i < 16; i++) {
            int n = i * 256 + tid;
            px[i] = xb[n]; py[i] = xb[NN + n]; pz[i] = xb[2 * NN + n];
            sxyz4[n] = make_float4(px[i], py[i], pz[i], 0.f);
            dist[i] = 1e10f;
        }
#pragma unroll
        for (int i = 0; i < 16; i++) {
            asm volatile("" : "+v"(px[i]));
            asm volatile("" : "+v"(py[i]));
            asm volatile("" : "+v"(pz[i]));
        }
        int far = 0;
        if (tid == 0) fbuf[0] = 0;
        __syncthreads();                 // covers sxyz4 + fbuf[0] fill
        for (int t = 0; t < NP; t++) {
            float4 c = sxyz4[far];                   // one ds_read_b128
            float cx = c.x, cy = c.y, cz = c.z;
            float bv = -1.0f; int bi = 0;
#pragma unroll
            for (int i = 0; i < 16; i++) {
                float dx = __fsub_rn(px[i], cx);
                float dy = __fsub_rn(py[i], cy);
                float dz = __fsub_rn(pz[i], cz);
                float d = __fadd_rn(__fadd_rn(__fmul_rn(dx, dx), __fmul_rn(dy, dy)),
                                    __fmul_rn(dz, dz));
                float nd = fminf(dist[i], d);
                dist[i] = nd;
                if (nd > bv) { bv = nd; bi = i; }    // cmp + 2 cndmask
            }
            int n_best = bi * 256 + tid;
            unsigned long long k =
                ((unsigned long long)__float_as_uint(bv) << 32) |
                (unsigned long long)(~(unsigned)n_best);
            k = dppmax<0x111, 0xf>(k);   // row_shr:1
            k = dppmax<0x112, 0xf>(k);   // row_shr:2
            k = dppmax<0x114, 0xf>(k);   // row_shr:4
            k = dppmax<0x118, 0xf>(k);   // row_shr:8
            k = dppmax<0x142, 0xa>(k);   // row_bcast:15
            k = dppmax<0x143, 0xc>(k);   // row_bcast:31
            if ((tid & 63) == 63) red[t & 1][wv] = k;
            // LDS-only barrier: order ds ops, never drain vmcnt.
            asm volatile("s_waitcnt lgkmcnt(0)\n\ts_barrier" ::: "memory");
            // chunked publish: one store instr per 16 iters, fire-and-forget
            if ((t & 15) == 15 && tid < 16) {
                int i = (t - 15) + tid;
                __hip_atomic_store(&fidx[b * NP + i], fbuf[i],
                                   __ATOMIC_RELAXED, __HIP_MEMORY_SCOPE_AGENT);
            }
            ulonglong2 ra = *(ulonglong2*)&red[t & 1][0];
            ulonglong2 rb = *(ulonglong2*)&red[t & 1][2];
            unsigned long long r0 = ra.x, r1 = ra.y, r2 = rb.x, r3 = rb.y;
            if (r1 > r0) r0 = r1;
            if (r3 > r2) r2 = r3;
            if (r2 > r0) r0 = r2;
            far = (int)(~(unsigned)r0);   // low32 = ~n -> n
            if (tid == 0 && t + 1 < NP) fbuf[t + 1] = far;
        }
        return;
    }

    // ---------------- worker path ----------------
    int w = blockIdx.x - 16;     // 0..239
    // ---- phase A: T transform, grid-strided over 65536 points ----
    for (int j = 0; j < 2; j++) {
        int gid = w * 256 + tid + j * (NWRK * 256);   // b*4096 + n
        if (gid < NB * NN) {
            int b = gid >> 12, n = gid & (NN - 1);
            const float* xb = xyz + (size_t)b * 3 * NN;
            const float* pb = points + (size_t)b * 64 * NN;
            float acc[64];
#pragma unroll
            for (int o = 0; o < 64; o++) acc[o] = 0.f;
            for (int c = 0; c < 67; c++) {
                float v = (c < 3) ? xb[c * NN + n] : pb[(c - 3) * NN + n];
#pragma unroll
                for (int o = 0; o < 64; o++) acc[o] = fmaf(v, w0[o * 67 + c], acc[o]);
            }
            unsigned short* dst = T + (size_t)gid * 64;
            for (int oo = 0; oo < 64; oo += 8) {
                union { unsigned short u[8]; uint4 v; } r;
#pragma unroll
                for (int jj = 0; jj < 8; jj++) r.u[jj] = f2bf(acc[oo + jj]);
                *(uint4*)&dst[oo] = r.v;
            }
        }
    }
    // ---- phase B: worker barrier (T fully visible before any group reads) ----
    __syncthreads();
    __threadfence();             // release T stores
    if (tid == 0) {
        __hip_atomic_fetch_add(sync_ctr, 1, __ATOMIC_ACQ_REL, __HIP_MEMORY_SCOPE_AGENT);
        while (__hip_atomic_load(sync_ctr, __ATOMIC_ACQUIRE, __HIP_MEMORY_SCOPE_AGENT) < NWRK)
            __builtin_amdgcn_s_sleep(32);
    }
    __syncthreads();
    __threadfence();             // acquire side

    // ---- phase C: s-major quad order; spin per-wave on fidx[g] ----
    {
        int b = w & 15;          // fixed batch per worker
        int r = w >> 4;          // k-lane 0..14
        const float* xb = xyz + (size_t)b * 3 * NN;
        const unsigned short* Tb = T + (size_t)b * NN * 64;
        for (int kk = r; kk < 256; kk += 15) {
            int s = (kk << 2) + wv;                  // monotone in loop
            int g = (b << 10) + s;
            int fid;
            if (lane == 0) {
                fid = __hip_atomic_load(&fidx[g], __ATOMIC_RELAXED, __HIP_MEMORY_SCOPE_AGENT);
                while (fid < 0) {
                    __builtin_amdgcn_s_sleep(16);
                    fid = __hip_atomic_load(&fidx[g], __ATOMIC_RELAXED, __HIP_MEMORY_SCOPE_AGENT);
                }
            }
            fid = __shfl(fid, 0);
            float cx = xb[fid], cy = xb[NN + fid], cz = xb[2 * NN + fid];
            if (lane < 3) {
                float v = (lane == 0) ? cx : ((lane == 1) ? cy : cz);
                out0[((size_t)b * 3 + lane) * NP + s] = v;
            }
            float sa = __fadd_rn(__fadd_rn(__fmul_rn(cx, cx), __fmul_rn(cy, cy)),
                                 __fmul_rn(cz, cz));
            int* out = idx + (size_t)g * NS;
            int total = 0; int first = 0;
            for (int ci = 0; ci < NN / 64; ci++) {
                int n = ci * 64 + lane;
                float x = xb[n], y = xb[NN + n], z = xb[2 * NN + n];
                float sb = __fadd_rn(__fadd_rn(__fmul_rn(x, x), __fmul_rn(y, y)),
                                     __fmul_rn(z, z));
                float dot = __fadd_rn(__fadd_rn(__fmul_rn(x, cx), __fmul_rn(y, cy)),
                                      __fmul_rn(z, cz));
                float sqr = __fsub_rn(__fadd_rn(sa, sb), __fmul_rn(2.0f, dot));
                bool pred = !(sqr > 0.04f);
                unsigned long long mask = __ballot(pred);
                if (mask) {
                    if (total == 0) first = ci * 64 + (int)__builtin_ctzll(mask);
                    int pos = total + (int)__popcll(mask & ((1ull << lane) - 1ull));
                    if (pred && pos < NS) { out[pos] = n; gidx[wv][pos] = n; }
                    total += (int)__popcll(mask);
                    if (total >= NS) break;
                }
            }
            if (total < NS) {
                if (lane >= total && lane < NS) { out[lane] = first; gidx[wv][lane] = first; }
            }
            // ---- BN1 stats: lane = channel o ----
            int o = lane;
            float uo = fmaf(w0[o * 67 + 2], cz, fmaf(w0[o * 67 + 1], cy, w0[o * 67] * cx));
            float bo = b0[o];
            float s1 = 0.f, s2 = 0.f;
            for (int k = 0; k < NS; k++) {
                int n = gidx[wv][k];
                float tv = bf2f(Tb[(size_t)n * 64 + o]);
                float h = tv - uo + bo;
                s1 += h; s2 = fmaf(h, h, s2);
            }
            int slot = g & 63;
            atomicAdd(&stage1[slot * 128 + o], (double)s1);
            atomicAdd(&stage1[slot * 128 + 64 + o], (double)s2);
        }
    }
}

// =====================================================================
// TAIL (round-6): ONE persistent kernel replacing finalize1/2/3 +
// layer2 + layer3 + epilogue (7 dispatches -> 1).
// Grid = 1024 = 4 blocks/CU x 256 CU EXACT capacity:
//   LDS 39.9KB <= 40KB/block, __launch_bounds__(256,4) caps VGPR<=128
//   -> all blocks co-resident -> grid barriers deadlock-free.
// Cross-block data flow is ONLY the BN stat sums (h2, mx/mn are
// same-block produce/consume) -> 2 grid barriers total. Finalizes are
// computed REDUNDANTLY per block into LDS (64x2 f64 L2 loads, ~2us) —
// no serial section, no extra release barrier.
// Block owns 16 consecutive groups (4 quads): g = blk*16 + it*4 + wv.
// =====================================================================
__global__ __launch_bounds__(256, 4) void tail_kernel(
        const float* __restrict__ xyz, const unsigned short* __restrict__ T,
        const int* __restrict__ fidx, const int* __restrict__ idx,
        const float* __restrict__ w0, const float* __restrict__ b0,
        const double* __restrict__ stage1, const float* __restrict__ g0v, const float* __restrict__ bt0v,
        const float* __restrict__ w1, const float* __restrict__ b1,
        double* __restrict__ stage2, const float* __restrict__ g1v, const float* __restrict__ bt1v,
        const float* __restrict__ w2, const float* __restrict__ b2,
        double* __restrict__ stage3, const float* __restrict__ g2v, const float* __restrict__ bt2v,
        unsigned short* __restrict__ h2, float* __restrict__ mxbuf, float* __restrict__ mnbuf,
        float* __restrict__ out1, int* __restrict__ bar_ctr, int* __restrict__ bar_gen) {
    __shared__ union {
        struct { unsigned short w1s[64][72]; unsigned short h1s[4][32][72]; } A;   // 27.0 KB
        struct { unsigned short w2s[128][72]; unsigned short h2s[4][32][72]; } B;  // 36.0 KB
        struct { float tile[128][17]; } C;                                         //  8.5 KB
    } sm;
    __shared__ float psum[128], psq[128];          // 1 KB (phases A uses 64)
    __shared__ float ab1[128], ab2[128], ab3[256]; // 2 KB
    int t = threadIdx.x, wv = t >> 6, lane = t & 63;
    int quad = lane >> 4, col = lane & 15;
    int blk = blockIdx.x;

    // ---- finalize1 (redundant per block; stage1 complete via stream order) ----
    if (t < 64) {
        double s = 0.0, q = 0.0;
        for (int i = 0; i < 64; i++) { s += stage1[i * 128 + t]; q += stage1[i * 128 + 64 + t]; }
        double m = s * (1.0 / CNT);
        double v = q * (1.0 / CNT) - m * m;
        double A = (double)g0v[t] / sqrt(v + 1e-5);
        ab1[t] = (float)A;
        ab1[64 + t] = (float)((double)bt0v[t] - m * A);
    }
    for (int lin = t; lin < 4096; lin += 256)
        sm.A.w1s[lin >> 6][lin & 63] = f2bf(w1[lin]);
    __syncthreads();

    // ================= phase A: layer2 over 4 quads =================
    for (int it = 0; it < 4; it++) {
        int qq = blk * 4 + it;
        int g = qq * 4 + wv;
        int b = g >> 10;
        if (t < 64) { psum[t] = 0.f; psq[t] = 0.f; }
        {   // rebuild normalized h1 (bf16) into LDS [k][o], lane = o
            int fid = fidx[g];
            const float* xb = xyz + (size_t)b * 3 * NN;
            float cx = xb[fid], cy = xb[NN + fid], cz = xb[2 * NN + fid];
            int o = lane;
            float uo = fmaf(w0[o * 67 + 2], cz, fmaf(w0[o * 67 + 1], cy, w0[o * 67] * cx));
            float bo = b0[o];
            float a1 = ab1[o], bb1 = ab1[64 + o];
            const int* gi = idx + (size_t)g * NS;
            const unsigned short* Tb = T + (size_t)b * NN * 64;
            for (int k = 0; k < NS; k++) {
                int n = gi[k];
                float tv = bf2f(Tb[(size_t)n * 64 + o]);
                float h = tv - uo + bo;
                float hn = fmaxf(fmaf(h, a1, bb1), 0.f);
                sm.A.h1s[wv][k][o] = f2bf(hn);
            }
        }
        __syncthreads();
        f32x4 acc[2][4];
#pragma unroll
        for (int i = 0; i < 2; i++)
#pragma unroll
            for (int j = 0; j < 4; j++) acc[i][j] = (f32x4){0.f, 0.f, 0.f, 0.f};
#pragma unroll
        for (int ks = 0; ks < 2; ks++) {
            bf16x8 a0 = as_bf(*(const uint4*)&sm.A.h1s[wv][col][ks * 32 + quad * 8]);
            bf16x8 a1f = as_bf(*(const uint4*)&sm.A.h1s[wv][16 + col][ks * 32 + quad * 8]);
#pragma unroll
            for (int nt = 0; nt < 4; nt++) {
                bf16x8 bf = as_bf(*(const uint4*)&sm.A.w1s[nt * 16 + col][ks * 32 + quad * 8]);
                acc[0][nt] = __builtin_amdgcn_mfma_f32_16x16x32_bf16(a0, bf, acc[0][nt], 0, 0, 0);
                acc[1][nt] = __builtin_amdgcn_mfma_f32_16x16x32_bf16(a1f, bf, acc[1][nt], 0, 0, 0);
            }
        }
        float s1[4], s2[4];
#pragma unroll
        for (int nt = 0; nt < 4; nt++) {
            float bb = b1[nt * 16 + col];
            s1[nt] = 0.f; s2[nt] = 0.f;
#pragma unroll
            for (int mt = 0; mt < 2; mt++)
#pragma unroll
                for (int r = 0; r < 4; r++) {
                    float v = acc[mt][nt][r] + bb;
                    s1[nt] += v; s2[nt] = fmaf(v, v, s2[nt]);
                    sm.A.h1s[wv][mt * 16 + quad * 4 + r][nt * 16 + col] = f2bf(v);
                }
            s1[nt] += __shfl_xor(s1[nt], 16); s1[nt] += __shfl_xor(s1[nt], 32);
            s2[nt] += __shfl_xor(s2[nt], 16); s2[nt] += __shfl_xor(s2[nt], 32);
            if (quad == 0) {
                atomicAdd(&psum[nt * 16 + col], s1[nt]);
                atomicAdd(&psq[nt * 16 + col], s2[nt]);
            }
        }
#pragma unroll
        for (int r = 0; r < 4; r++) {
            int lin = lane + 64 * r;
            int row = lin >> 3, c = lin & 7;
            uint4 v = *(const uint4*)&sm.A.h1s[wv][row][c * 8];
            *(uint4*)&h2[((size_t)g * NS + row) * 64 + c * 8] = v;
        }
        __syncthreads();
        if (t < 64) {
            int slot = qq & 63;
            atomicAdd(&stage2[slot * 128 + t], (double)psum[t]);
            atomicAdd(&stage2[slot * 128 + 64 + t], (double)psq[t]);
        }
        __syncthreads();
    }

    // ---- grid barrier 1 (all stats2 atomics done) ----
    __syncthreads();
    __threadfence();
    if (t == 0) {
        int n = __hip_atomic_fetch_add(bar_ctr, 1, __ATOMIC_ACQ_REL, __HIP_MEMORY_SCOPE_AGENT);
        if (n == TGRID - 1) {
            __hip_atomic_store(bar_ctr, 0, __ATOMIC_RELAXED, __HIP_MEMORY_SCOPE_AGENT);
            __hip_atomic_store(bar_gen, 1, __ATOMIC_RELEASE, __HIP_MEMORY_SCOPE_AGENT);
        } else {
            while (__hip_atomic_load(bar_gen, __ATOMIC_ACQUIRE, __HIP_MEMORY_SCOPE_AGENT) < 1)
                __builtin_amdgcn_s_sleep(8);
        }
    }
    __syncthreads();
    __threadfence();

    // ---- finalize2 (redundant) + w2 load ----
    if (t < 64) {
        double s = 0.0, q = 0.0;
        for (int i = 0; i < 64; i++) { s += stage2[i * 128 + t]; q += stage2[i * 128 + 64 + t]; }
        double m = s * (1.0 / CNT);
        double v = q * (1.0 / CNT) - m * m;
        double A = (double)g1v[t] / sqrt(v + 1e-5);
        ab2[t] = (float)A;
        ab2[64 + t] = (float)((double)bt1v[t] - m * A);
    }
    for (int lin = t; lin < 8192; lin += 256)
        sm.B.w2s[lin >> 6][lin & 63] = f2bf(w2[lin]);
    __syncthreads();

    // ================= phase B: layer3 over 4 quads =================
    for (int it = 0; it < 4; it++) {
        int qq = blk * 4 + it;
        int g = qq * 4 + wv;
        if (t < 128) { psum[t] = 0.f; psq[t] = 0.f; }
        {   // h2 -> BN2+relu -> LDS bf16. lane owns channels c*8..c*8+7
            int c = lane & 7;
            float a2v[8], bb2v[8];
#pragma unroll
            for (int j = 0; j < 8; j++) {
                a2v[j] = ab2[c * 8 + j];
                bb2v[j] = ab2[64 + c * 8 + j];
            }
            const unsigned short* hg = h2 + (size_t)g * NS * 64;
#pragma unroll
            for (int r = 0; r < 4; r++) {
                int row = (lane >> 3) + 8 * r;
                union { uint4 v; unsigned short u[8]; } in, outp;
                in.v = *(const uint4*)&hg[row * 64 + c * 8];
#pragma unroll
                for (int j = 0; j < 8; j++) {
                    float f = bf2f(in.u[j]);
                    outp.u[j] = f2bf(fmaxf(fmaf(f, a2v[j], bb2v[j]), 0.f));
                }
                *(uint4*)&sm.B.h2s[wv][row][c * 8] = outp.v;
            }
        }
        __syncthreads();
        f32x4 acc[2][8];
#pragma unroll
        for (int i = 0; i < 2; i++)
#pragma unroll
            for (int j = 0; j < 8; j++) acc[i][j] = (f32x4){0.f, 0.f, 0.f, 0.f};
#pragma unroll
        for (int ks = 0; ks < 2; ks++) {
            bf16x8 a0 = as_bf(*(const uint4*)&sm.B.h2s[wv][col][ks * 32 + quad * 8]);
            bf16x8 a1f = as_bf(*(const uint4*)&sm.B.h2s[wv][16 + col][ks * 32 + quad * 8]);
#pragma unroll
            for (int nt = 0; nt < 8; nt++) {
                bf16x8 bf = as_bf(*(const uint4*)&sm.B.w2s[nt * 16 + col][ks * 32 + quad * 8]);
                acc[0][nt] = __builtin_amdgcn_mfma_f32_16x16x32_bf16(a0, bf, acc[0][nt], 0, 0, 0);
                acc[1][nt] = __builtin_amdgcn_mfma_f32_16x16x32_bf16(a1f, bf, acc[1][nt], 0, 0, 0);
            }
        }
#pragma unroll
        for (int nt = 0; nt < 8; nt++) {
            float bb = b2[nt * 16 + col];
            float s1 = 0.f, s2 = 0.f, mx = -1e30f, mn = 1e30f;
#pragma unroll
            for (int mt = 0; mt < 2; mt++)
#pragma unroll
                for (int r = 0; r < 4; r++) {
                    float v = acc[mt][nt][r] + bb;
                    s1 += v; s2 = fmaf(v, v, s2);
                    mx = fmaxf(mx, v); mn = fminf(mn, v);
                }
            s1 += __shfl_xor(s1, 16); s1 += __shfl_xor(s1, 32);
            s2 += __shfl_xor(s2, 16); s2 += __shfl_xor(s2, 32);
            mx = fmaxf(mx, __shfl_xor(mx, 16)); mx = fmaxf(mx, __shfl_xor(mx, 32));
            mn = fminf(mn, __shfl_xor(mn, 16)); mn = fminf(mn, __shfl_xor(mn, 32));
            if (quad == 0) {
                atomicAdd(&psum[nt * 16 + col], s1);
                atomicAdd(&psq[nt * 16 + col], s2);
                mxbuf[(size_t)g * 128 + nt * 16 + col] = mx;
                mnbuf[(size_t)g * 128 + nt * 16 + col] = mn;
            }
        }
        __syncthreads();
        if (t < 128) {
            int slot = qq & 63;
            atomicAdd(&stage3[slot * 256 + t], (double)psum[t]);
            atomicAdd(&stage3[slot * 256 + 128 + t], (double)psq[t]);
        }
        __syncthreads();
    }

    // ---- grid barrier 2 (all stats3 atomics done) ----
    __syncthreads();
    __threadfence();
    if (t == 0) {
        int n = __hip_atomic_fetch_add(bar_ctr, 1, __ATOMIC_ACQ_REL, __HIP_MEMORY_SCOPE_AGENT);
        if (n == TGRID - 1) {
            __hip_atomic_store(bar_ctr, 0, __ATOMIC_RELAXED, __HIP_MEMORY_SCOPE_AGENT);
            __hip_atomic_store(bar_gen, 2, __ATOMIC_RELEASE, __HIP_MEMORY_SCOPE_AGENT);
        } else {
            while (__hip_atomic_load(bar_gen, __ATOMIC_ACQUIRE, __HIP_MEMORY_SCOPE_AGENT) < 2)
                __builtin_amdgcn_s_sleep(8);
        }
    }
    __syncthreads();
    __threadfence();

    // ---- finalize3 (redundant) ----
    if (t < 128) {
        double s = 0.0, q = 0.0;
        for (int i = 0; i < 64; i++) { s += stage3[i * 256 + t]; q += stage3[i * 256 + 128 + t]; }
        double m = s * (1.0 / CNT);
        double v = q * (1.0 / CNT) - m * m;
        double A = (double)g2v[t] / sqrt(v + 1e-5);
        ab3[t] = (float)A;
        ab3[128 + t] = (float)((double)bt2v[t] - m * A);
    }
    __syncthreads();

    // ================= phase C: epilogue for this block's 16 groups ====
    {
        int gbase = blk * 16;                      // 16 consecutive groups, same batch
        int b = gbase >> 10, s0 = gbase & 1023;
        for (int j = 0; j < 8; j++) {
            int lin = t + 256 * j;                 // 0..2047
            int sl = lin >> 7, o = lin & 127;
            float a = ab3[o], bb = ab3[128 + o];
            size_t src = (size_t)(gbase + sl) * 128 + o;   // own block's writes -> L2 hit
            float v = (a >= 0.f) ? mxbuf[src] : mnbuf[src];
            sm.C.tile[o][sl] = fmaxf(fmaf(v, a, bb), 0.f);
        }
        __syncthreads();
        for (int j = 0; j < 8; j++) {
            int lin = t + 256 * j;
            int o = lin >> 4, sl = lin & 15;
            out1[((size_t)b * 128 + o) * NP + s0 + sl] = sm.C.tile[o][sl];
        }
    }
}

// =====================================================================
extern "C" void kernel_launch(void* const* d_in, const int* in_sizes, int n_in,
                              void* d_out, int out_size, void* d_ws, size_t ws_size,
                              hipStream_t stream) {
    const float* xyz    = (const float*)d_in[0];
    const float* points = (const float*)d_in[1];
    const float* w0  = (const float*)d_in[2];
    const float* b0  = (const float*)d_in[3];
    const float* g0  = (const float*)d_in[4];
    const float* bt0 = (const float*)d_in[5];
    const float* w1  = (const float*)d_in[6];
    const float* b1  = (const float*)d_in[7];
    const float* g1  = (const float*)d_in[8];
    const float* bt1 = (const float*)d_in[9];
    const float* w2  = (const float*)d_in[10];
    const float* b2  = (const float*)d_in[11];
    const float* g2  = (const float*)d_in[12];
    const float* bt2 = (const float*)d_in[13];

    char* ws = (char*)d_ws;
    // workspace layout (bytes, 256-aligned): total ~94.7 MB
    int*            fidx = (int*)(ws + 0);                       //   64 KB
    int*            idx  = (int*)(ws + 65536);                   //    2 MB
    unsigned short* T    = (unsigned short*)(ws + 2162688);      //  8.4 MB bf16
    unsigned short* h2   = (unsigned short*)(ws + 10551296);     //   67 MB bf16
    float*          mxbuf = (float*)(ws + 77660160);             //  8.4 MB
    float*          mnbuf = (float*)(ws + 86048768);             //  8.4 MB
    double*         stage = (double*)(ws + 94437376);            //  256 KB
    int*            sync_ctr = (int*)(ws + 94701312);            // fused worker barrier
    int*            bar_ctr  = (int*)(ws + 94701316);            // tail grid barrier ctr
    int*            bar_gen  = (int*)(ws + 94701320);            // tail barrier generation
    double* stage1 = stage;
    double* stage2 = stage + 64 * 128;
    double* stage3 = stage + 2 * 64 * 128;
    float* out0 = (float*)d_out;
    float* out1 = out0 + NB * 3 * NP;

    hipMemsetAsync(stage, 0, 262144, stream);        // zero stat slots
    hipMemsetAsync(fidx, 0xFF, NB * NP * 4, stream); // fidx = -1 (spin flags)
    hipMemsetAsync(sync_ctr, 0, 12, stream);         // sync_ctr + bar_ctr + bar_gen

    fused_kernel<<<256, 256, 0, stream>>>(xyz, points, w0, b0, fidx, T, idx,
                                          stage1, out0, sync_ctr);
    tail_kernel<<<TGRID, 256, 0, stream>>>(xyz, T, fidx, idx, w0, b0,
                                           stage1, g0, bt0,
                                           w1, b1, stage2, g1, bt1,
                                           w2, b2, stage3, g2, bt2,
                                           h2, mxbuf, mnbuf, out1,
                                           bar_ctr, bar_gen);
}

// Round 7
// 1097.753 us; speedup vs baseline: 1.3163x; 1.3163x over previous
//
#include <hip/hip_runtime.h>
#include <stdint.h>

// Problem constants
#define NB    16
#define NN    4096
#define NP    1024
#define NS    32
#define NGRP  (NB*NP)          // 16384 groups
#define CNT   524288.0         // B*K*S elements per channel for BN stats
#define NWRK  240              // worker blocks (grid 256 = 16 FPS + 240)
#define TGRID 512              // tail grid: 2 blocks/CU x 256 CU (VGPR<=256, no spill)

typedef short  bf16x8 __attribute__((ext_vector_type(8)));
typedef float  f32x4  __attribute__((ext_vector_type(4)));

// ---------- bf16 helpers (RNE) ----------
__device__ __forceinline__ float bf2f(unsigned short u) {
    return __uint_as_float(((unsigned)u) << 16);
}
__device__ __forceinline__ unsigned short f2bf(float f) {
    unsigned u = __float_as_uint(f);
    unsigned r = u + 0x7fffu + ((u >> 16) & 1u);
    return (unsigned short)(r >> 16);
}
__device__ __forceinline__ bf16x8 as_bf(uint4 u) {
    union { uint4 a; bf16x8 b; } c; c.a = u; return c.b;
}

// u64 max with one DPP step (compare-select). VALU-only.
template <int CTRL, int RM>
__device__ __forceinline__ unsigned long long dppmax(unsigned long long k) {
    int lo = (int)(unsigned)k;
    int hi = (int)(k >> 32);
    int ml = __builtin_amdgcn_update_dpp(lo, lo, CTRL, RM, 0xf, false);
    int mh = __builtin_amdgcn_update_dpp(hi, hi, CTRL, RM, 0xf, false);
    unsigned long long m = ((unsigned long long)(unsigned)mh << 32) | (unsigned)ml;
    return m > k ? m : k;
}

// =====================================================================
// FUSED K1 (r5, measured 636us): blocks 0..15 FPS w/ chunked publish;
// blocks 16..255 workers: T transform -> barrier -> s-major group quads.
// =====================================================================
__global__ __launch_bounds__(256, 1) void fused_kernel(const float* __restrict__ xyz,
                                                       const float* __restrict__ points,
                                                       const float* __restrict__ w0,
                                                       const float* __restrict__ b0,
                                                       int* __restrict__ fidx,
                                                       unsigned short* __restrict__ T,
                                                       int* __restrict__ idx,
                                                       double* __restrict__ stage1,
                                                       float* __restrict__ out0,
                                                       int* __restrict__ sync_ctr) {
    __shared__ float4 sxyz4[NN];                    // 64 KB (FPS centroid cache)
    __shared__ unsigned long long red[2][4];        // FPS: parity x wave slots
    __shared__ int fbuf[NP];                        // FPS: result staging (LDS)
    __shared__ int gidx[4][NS];                     // group: per-wave ball idx
    int tid = threadIdx.x;
    int wv = tid >> 6, lane = tid & 63;

    if (blockIdx.x < 16) {
        // ---------------- FPS path (round-0 body + chunked publish) ----
        int b = blockIdx.x;
        const float* xb = xyz + (size_t)b * 3 * NN;
        float px[16], py[16], pz[16], dist[16];
#pragma unroll
        for (int i = 0; i < 16; i++) {
            int n = i * 256 + tid;
            px[i] = xb[n]; py[i] = xb[NN + n]; pz[i] = xb[2 * NN + n];
            sxyz4[n] = make_float4(px[i], py[i], pz[i], 0.f);
            dist[i] = 1e10f;
        }
#pragma unroll
        for (int i = 0; i < 16; i++) {
            asm volatile("" : "+v"(px[i]));
            asm volatile("" : "+v"(py[i]));
            asm volatile("" : "+v"(pz[i]));
        }
        int far = 0;
        if (tid == 0) fbuf[0] = 0;
        __syncthreads();                 // covers sxyz4 + fbuf[0] fill
        for (int t = 0; t < NP; t++) {
            float4 c = sxyz4[far];                   // one ds_read_b128
            float cx = c.x, cy = c.y, cz = c.z;
            float bv = -1.0f; int bi = 0;
#pragma unroll
            for (int i = 0; i < 16; i++) {
                float dx = __fsub_rn(px[i], cx);
                float dy = __fsub_rn(py[i], cy);
                float dz = __fsub_rn(pz[i], cz);
                float d = __fadd_rn(__fadd_rn(__fmul_rn(dx, dx), __fmul_rn(dy, dy)),
                                    __fmul_rn(dz, dz));
                float nd = fminf(dist[i], d);
                dist[i] = nd;
                if (nd > bv) { bv = nd; bi = i; }    // cmp + 2 cndmask
            }
            int n_best = bi * 256 + tid;
            unsigned long long k =
                ((unsigned long long)__float_as_uint(bv) << 32) |
                (unsigned long long)(~(unsigned)n_best);
            k = dppmax<0x111, 0xf>(k);   // row_shr:1
            k = dppmax<0x112, 0xf>(k);   // row_shr:2
            k = dppmax<0x114, 0xf>(k);   // row_shr:4
            k = dppmax<0x118, 0xf>(k);   // row_shr:8
            k = dppmax<0x142, 0xa>(k);   // row_bcast:15
            k = dppmax<0x143, 0xc>(k);   // row_bcast:31
            if ((tid & 63) == 63) red[t & 1][wv] = k;
            // LDS-only barrier: order ds ops, never drain vmcnt.
            asm volatile("s_waitcnt lgkmcnt(0)\n\ts_barrier" ::: "memory");
            // chunked publish: one store instr per 16 iters, fire-and-forget
            if ((t & 15) == 15 && tid < 16) {
                int i = (t - 15) + tid;
                __hip_atomic_store(&fidx[b * NP + i], fbuf[i],
                                   __ATOMIC_RELAXED, __HIP_MEMORY_SCOPE_AGENT);
            }
            ulonglong2 ra = *(ulonglong2*)&red[t & 1][0];
            ulonglong2 rb = *(ulonglong2*)&red[t & 1][2];
            unsigned long long r0 = ra.x, r1 = ra.y, r2 = rb.x, r3 = rb.y;
            if (r1 > r0) r0 = r1;
            if (r3 > r2) r2 = r3;
            if (r2 > r0) r0 = r2;
            far = (int)(~(unsigned)r0);   // low32 = ~n -> n
            if (tid == 0 && t + 1 < NP) fbuf[t + 1] = far;
        }
        return;
    }

    // ---------------- worker path ----------------
    int w = blockIdx.x - 16;     // 0..239
    // ---- phase A: T transform, grid-strided over 65536 points ----
    for (int j = 0; j < 2; j++) {
        int gid = w * 256 + tid + j * (NWRK * 256);   // b*4096 + n
        if (gid < NB * NN) {
            int b = gid >> 12, n = gid & (NN - 1);
            const float* xb = xyz + (size_t)b * 3 * NN;
            const float* pb = points + (size_t)b * 64 * NN;
            float acc[64];
#pragma unroll
            for (int o = 0; o < 64; o++) acc[o] = 0.f;
            for (int c = 0; c < 67; c++) {
                float v = (c < 3) ? xb[c * NN + n] : pb[(c - 3) * NN + n];
#pragma unroll
                for (int o = 0; o < 64; o++) acc[o] = fmaf(v, w0[o * 67 + c], acc[o]);
            }
            unsigned short* dst = T + (size_t)gid * 64;
            for (int oo = 0; oo < 64; oo += 8) {
                union { unsigned short u[8]; uint4 v; } r;
#pragma unroll
                for (int jj = 0; jj < 8; jj++) r.u[jj] = f2bf(acc[oo + jj]);
                *(uint4*)&dst[oo] = r.v;
            }
        }
    }
    // ---- phase B: worker barrier (T fully visible before any group reads) ----
    __syncthreads();
    __threadfence();             // release T stores
    if (tid == 0) {
        __hip_atomic_fetch_add(sync_ctr, 1, __ATOMIC_ACQ_REL, __HIP_MEMORY_SCOPE_AGENT);
        while (__hip_atomic_load(sync_ctr, __ATOMIC_ACQUIRE, __HIP_MEMORY_SCOPE_AGENT) < NWRK)
            __builtin_amdgcn_s_sleep(32);
    }
    __syncthreads();
    __threadfence();             // acquire side

    // ---- phase C: s-major quad order; spin per-wave on fidx[g] ----
    {
        int b = w & 15;          // fixed batch per worker
        int r = w >> 4;          // k-lane 0..14
        const float* xb = xyz + (size_t)b * 3 * NN;
        const unsigned short* Tb = T + (size_t)b * NN * 64;
        for (int kk = r; kk < 256; kk += 15) {
            int s = (kk << 2) + wv;                  // monotone in loop
            int g = (b << 10) + s;
            int fid;
            if (lane == 0) {
                fid = __hip_atomic_load(&fidx[g], __ATOMIC_RELAXED, __HIP_MEMORY_SCOPE_AGENT);
                while (fid < 0) {
                    __builtin_amdgcn_s_sleep(16);
                    fid = __hip_atomic_load(&fidx[g], __ATOMIC_RELAXED, __HIP_MEMORY_SCOPE_AGENT);
                }
            }
            fid = __shfl(fid, 0);
            float cx = xb[fid], cy = xb[NN + fid], cz = xb[2 * NN + fid];
            if (lane < 3) {
                float v = (lane == 0) ? cx : ((lane == 1) ? cy : cz);
                out0[((size_t)b * 3 + lane) * NP + s] = v;
            }
            float sa = __fadd_rn(__fadd_rn(__fmul_rn(cx, cx), __fmul_rn(cy, cy)),
                                 __fmul_rn(cz, cz));
            int* out = idx + (size_t)g * NS;
            int total = 0; int first = 0;
            for (int ci = 0; ci < NN / 64; ci++) {
                int n = ci * 64 + lane;
                float x = xb[n], y = xb[NN + n], z = xb[2 * NN + n];
                float sb = __fadd_rn(__fadd_rn(__fmul_rn(x, x), __fmul_rn(y, y)),
                                     __fmul_rn(z, z));
                float dot = __fadd_rn(__fadd_rn(__fmul_rn(x, cx), __fmul_rn(y, cy)),
                                      __fmul_rn(z, cz));
                float sqr = __fsub_rn(__fadd_rn(sa, sb), __fmul_rn(2.0f, dot));
                bool pred = !(sqr > 0.04f);
                unsigned long long mask = __ballot(pred);
                if (mask) {
                    if (total == 0) first = ci * 64 + (int)__builtin_ctzll(mask);
                    int pos = total + (int)__popcll(mask & ((1ull << lane) - 1ull));
                    if (pred && pos < NS) { out[pos] = n; gidx[wv][pos] = n; }
                    total += (int)__popcll(mask);
                    if (total >= NS) break;
                }
            }
            if (total < NS) {
                if (lane >= total && lane < NS) { out[lane] = first; gidx[wv][lane] = first; }
            }
            // ---- BN1 stats: lane = channel o ----
            int o = lane;
            float uo = fmaf(w0[o * 67 + 2], cz, fmaf(w0[o * 67 + 1], cy, w0[o * 67] * cx));
            float bo = b0[o];
            float s1 = 0.f, s2 = 0.f;
            for (int k = 0; k < NS; k++) {
                int n = gidx[wv][k];
                float tv = bf2f(Tb[(size_t)n * 64 + o]);
                float h = tv - uo + bo;
                s1 += h; s2 = fmaf(h, h, s2);
            }
            int slot = g & 63;
            atomicAdd(&stage1[slot * 128 + o], (double)s1);
            atomicAdd(&stage1[slot * 128 + 64 + o], (double)s2);
        }
    }
}

// =====================================================================
// TAIL (round-7): persistent kernel, finalize1/2/3 + layer2 + layer3 +
// epilogue in ONE dispatch. Round-6 failed at TGRID=1024/launch_bounds
// (256,4): VGPR capped at 64 while phase B holds acc[2][8]=64 f32 ->
// total scratch spill -> 748us at VALUBusy 5%. Fix: TGRID=512 =
// 2 blocks/CU, __launch_bounds__(256,2) -> VGPR cap 256, zero spill.
// Capacity: LDS 39.9KB x 2 = 79.9 <= 160KB, VGPR <= 256 -> 8 waves/CU
// = 2 blocks -> all 512 co-resident -> grid barriers deadlock-free.
// Block owns 32 groups: phases A/B loop 8 quads, phase C 2 tiles.
// =====================================================================
__global__ __launch_bounds__(256, 2) void tail_kernel(
        const float* __restrict__ xyz, const unsigned short* __restrict__ T,
        const int* __restrict__ fidx, const int* __restrict__ idx,
        const float* __restrict__ w0, const float* __restrict__ b0,
        const double* __restrict__ stage1, const float* __restrict__ g0v, const float* __restrict__ bt0v,
        const float* __restrict__ w1, const float* __restrict__ b1,
        double* __restrict__ stage2, const float* __restrict__ g1v, const float* __restrict__ bt1v,
        const float* __restrict__ w2, const float* __restrict__ b2,
        double* __restrict__ stage3, const float* __restrict__ g2v, const float* __restrict__ bt2v,
        unsigned short* __restrict__ h2, float* __restrict__ mxbuf, float* __restrict__ mnbuf,
        float* __restrict__ out1, int* __restrict__ bar_ctr, int* __restrict__ bar_gen) {
    __shared__ union {
        struct { unsigned short w1s[64][72]; unsigned short h1s[4][32][72]; } A;   // 27.0 KB
        struct { unsigned short w2s[128][72]; unsigned short h2s[4][32][72]; } B;  // 36.0 KB
        struct { float tile[128][17]; } C;                                         //  8.5 KB
    } sm;
    __shared__ float psum[128], psq[128];          // 1 KB
    __shared__ float ab1[128], ab2[128], ab3[256]; // 2 KB
    int t = threadIdx.x, wv = t >> 6, lane = t & 63;
    int quad = lane >> 4, col = lane & 15;
    int blk = blockIdx.x;

    // ---- finalize1 (redundant per block; stage1 complete via stream order) ----
    if (t < 64) {
        double s = 0.0, q = 0.0;
        for (int i = 0; i < 64; i++) { s += stage1[i * 128 + t]; q += stage1[i * 128 + 64 + t]; }
        double m = s * (1.0 / CNT);
        double v = q * (1.0 / CNT) - m * m;
        double A = (double)g0v[t] / sqrt(v + 1e-5);
        ab1[t] = (float)A;
        ab1[64 + t] = (float)((double)bt0v[t] - m * A);
    }
    for (int lin = t; lin < 4096; lin += 256)
        sm.A.w1s[lin >> 6][lin & 63] = f2bf(w1[lin]);
    __syncthreads();

    // ================= phase A: layer2 over 8 quads =================
    for (int it = 0; it < 8; it++) {
        int qq = blk * 8 + it;
        int g = qq * 4 + wv;
        int b = g >> 10;
        if (t < 64) { psum[t] = 0.f; psq[t] = 0.f; }
        {   // rebuild normalized h1 (bf16) into LDS [k][o], lane = o
            int fid = fidx[g];
            const float* xb = xyz + (size_t)b * 3 * NN;
            float cx = xb[fid], cy = xb[NN + fid], cz = xb[2 * NN + fid];
            int o = lane;
            float uo = fmaf(w0[o * 67 + 2], cz, fmaf(w0[o * 67 + 1], cy, w0[o * 67] * cx));
            float bo = b0[o];
            float a1 = ab1[o], bb1 = ab1[64 + o];
            const int* gi = idx + (size_t)g * NS;
            const unsigned short* Tb = T + (size_t)b * NN * 64;
            for (int k = 0; k < NS; k++) {
                int n = gi[k];
                float tv = bf2f(Tb[(size_t)n * 64 + o]);
                float h = tv - uo + bo;
                float hn = fmaxf(fmaf(h, a1, bb1), 0.f);
                sm.A.h1s[wv][k][o] = f2bf(hn);
            }
        }
        __syncthreads();
        f32x4 acc[2][4];
#pragma unroll
        for (int i = 0; i < 2; i++)
#pragma unroll
            for (int j = 0; j < 4; j++) acc[i][j] = (f32x4){0.f, 0.f, 0.f, 0.f};
#pragma unroll
        for (int ks = 0; ks < 2; ks++) {
            bf16x8 a0 = as_bf(*(const uint4*)&sm.A.h1s[wv][col][ks * 32 + quad * 8]);
            bf16x8 a1f = as_bf(*(const uint4*)&sm.A.h1s[wv][16 + col][ks * 32 + quad * 8]);
#pragma unroll
            for (int nt = 0; nt < 4; nt++) {
                bf16x8 bf = as_bf(*(const uint4*)&sm.A.w1s[nt * 16 + col][ks * 32 + quad * 8]);
                acc[0][nt] = __builtin_amdgcn_mfma_f32_16x16x32_bf16(a0, bf, acc[0][nt], 0, 0, 0);
                acc[1][nt] = __builtin_amdgcn_mfma_f32_16x16x32_bf16(a1f, bf, acc[1][nt], 0, 0, 0);
            }
        }
        float s1[4], s2[4];
#pragma unroll
        for (int nt = 0; nt < 4; nt++) {
            float bb = b1[nt * 16 + col];
            s1[nt] = 0.f; s2[nt] = 0.f;
#pragma unroll
            for (int mt = 0; mt < 2; mt++)
#pragma unroll
                for (int r = 0; r < 4; r++) {
                    float v = acc[mt][nt][r] + bb;
                    s1[nt] += v; s2[nt] = fmaf(v, v, s2[nt]);
                    sm.A.h1s[wv][mt * 16 + quad * 4 + r][nt * 16 + col] = f2bf(v);
                }
            s1[nt] += __shfl_xor(s1[nt], 16); s1[nt] += __shfl_xor(s1[nt], 32);
            s2[nt] += __shfl_xor(s2[nt], 16); s2[nt] += __shfl_xor(s2[nt], 32);
            if (quad == 0) {
                atomicAdd(&psum[nt * 16 + col], s1[nt]);
                atomicAdd(&psq[nt * 16 + col], s2[nt]);
            }
        }
#pragma unroll
        for (int r = 0; r < 4; r++) {
            int lin = lane + 64 * r;
            int row = lin >> 3, c = lin & 7;
            uint4 v = *(const uint4*)&sm.A.h1s[wv][row][c * 8];
            *(uint4*)&h2[((size_t)g * NS + row) * 64 + c * 8] = v;
        }
        __syncthreads();
        if (t < 64) {
            int slot = qq & 63;
            atomicAdd(&stage2[slot * 128 + t], (double)psum[t]);
            atomicAdd(&stage2[slot * 128 + 64 + t], (double)psq[t]);
        }
        __syncthreads();
    }

    // ---- grid barrier 1 (all stats2 atomics done) ----
    __syncthreads();
    __threadfence();
    if (t == 0) {
        int n = __hip_atomic_fetch_add(bar_ctr, 1, __ATOMIC_ACQ_REL, __HIP_MEMORY_SCOPE_AGENT);
        if (n == TGRID - 1) {
            __hip_atomic_store(bar_ctr, 0, __ATOMIC_RELAXED, __HIP_MEMORY_SCOPE_AGENT);
            __hip_atomic_store(bar_gen, 1, __ATOMIC_RELEASE, __HIP_MEMORY_SCOPE_AGENT);
        } else {
            while (__hip_atomic_load(bar_gen, __ATOMIC_ACQUIRE, __HIP_MEMORY_SCOPE_AGENT) < 1)
                __builtin_amdgcn_s_sleep(8);
        }
    }
    __syncthreads();
    __threadfence();

    // ---- finalize2 (redundant) + w2 load ----
    if (t < 64) {
        double s = 0.0, q = 0.0;
        for (int i = 0; i < 64; i++) { s += stage2[i * 128 + t]; q += stage2[i * 128 + 64 + t]; }
        double m = s * (1.0 / CNT);
        double v = q * (1.0 / CNT) - m * m;
        double A = (double)g1v[t] / sqrt(v + 1e-5);
        ab2[t] = (float)A;
        ab2[64 + t] = (float)((double)bt1v[t] - m * A);
    }
    for (int lin = t; lin < 8192; lin += 256)
        sm.B.w2s[lin >> 6][lin & 63] = f2bf(w2[lin]);
    __syncthreads();

    // ================= phase B: layer3 over 8 quads =================
    for (int it = 0; it < 8; it++) {
        int qq = blk * 8 + it;
        int g = qq * 4 + wv;
        if (t < 128) { psum[t] = 0.f; psq[t] = 0.f; }
        {   // h2 -> BN2+relu -> LDS bf16. lane owns channels c*8..c*8+7
            int c = lane & 7;
            float a2v[8], bb2v[8];
#pragma unroll
            for (int j = 0; j < 8; j++) {
                a2v[j] = ab2[c * 8 + j];
                bb2v[j] = ab2[64 + c * 8 + j];
            }
            const unsigned short* hg = h2 + (size_t)g * NS * 64;
#pragma unroll
            for (int r = 0; r < 4; r++) {
                int row = (lane >> 3) + 8 * r;
                union { uint4 v; unsigned short u[8]; } in, outp;
                in.v = *(const uint4*)&hg[row * 64 + c * 8];
#pragma unroll
                for (int j = 0; j < 8; j++) {
                    float f = bf2f(in.u[j]);
                    outp.u[j] = f2bf(fmaxf(fmaf(f, a2v[j], bb2v[j]), 0.f));
                }
                *(uint4*)&sm.B.h2s[wv][row][c * 8] = outp.v;
            }
        }
        __syncthreads();
        f32x4 acc[2][8];
#pragma unroll
        for (int i = 0; i < 2; i++)
#pragma unroll
            for (int j = 0; j < 8; j++) acc[i][j] = (f32x4){0.f, 0.f, 0.f, 0.f};
#pragma unroll
        for (int ks = 0; ks < 2; ks++) {
            bf16x8 a0 = as_bf(*(const uint4*)&sm.B.h2s[wv][col][ks * 32 + quad * 8]);
            bf16x8 a1f = as_bf(*(const uint4*)&sm.B.h2s[wv][16 + col][ks * 32 + quad * 8]);
#pragma unroll
            for (int nt = 0; nt < 8; nt++) {
                bf16x8 bf = as_bf(*(const uint4*)&sm.B.w2s[nt * 16 + col][ks * 32 + quad * 8]);
                acc[0][nt] = __builtin_amdgcn_mfma_f32_16x16x32_bf16(a0, bf, acc[0][nt], 0, 0, 0);
                acc[1][nt] = __builtin_amdgcn_mfma_f32_16x16x32_bf16(a1f, bf, acc[1][nt], 0, 0, 0);
            }
        }
#pragma unroll
        for (int nt = 0; nt < 8; nt++) {
            float bb = b2[nt * 16 + col];
            float s1 = 0.f, s2 = 0.f, mx = -1e30f, mn = 1e30f;
#pragma unroll
            for (int mt = 0; mt < 2; mt++)
#pragma unroll
                for (int r = 0; r < 4; r++) {
                    float v = acc[mt][nt][r] + bb;
                    s1 += v; s2 = fmaf(v, v, s2);
                    mx = fmaxf(mx, v); mn = fminf(mn, v);
                }
            s1 += __shfl_xor(s1, 16); s1 += __shfl_xor(s1, 32);
            s2 += __shfl_xor(s2, 16); s2 += __shfl_xor(s2, 32);
            mx = fmaxf(mx, __shfl_xor(mx, 16)); mx = fmaxf(mx, __shfl_xor(mx, 32));
            mn = fminf(mn, __shfl_xor(mn, 16)); mn = fminf(mn, __shfl_xor(mn, 32));
            if (quad == 0) {
                atomicAdd(&psum[nt * 16 + col], s1);
                atomicAdd(&psq[nt * 16 + col], s2);
                mxbuf[(size_t)g * 128 + nt * 16 + col] = mx;
                mnbuf[(size_t)g * 128 + nt * 16 + col] = mn;
            }
        }
        __syncthreads();
        if (t < 128) {
            int slot = qq & 63;
            atomicAdd(&stage3[slot * 256 + t], (double)psum[t]);
            atomicAdd(&stage3[slot * 256 + 128 + t], (double)psq[t]);
        }
        __syncthreads();
    }

    // ---- grid barrier 2 (all stats3 atomics done) ----
    __syncthreads();
    __threadfence();
    if (t == 0) {
        int n = __hip_atomic_fetch_add(bar_ctr, 1, __ATOMIC_ACQ_REL, __HIP_MEMORY_SCOPE_AGENT);
        if (n == TGRID - 1) {
            __hip_atomic_store(bar_ctr, 0, __ATOMIC_RELAXED, __HIP_MEMORY_SCOPE_AGENT);
            __hip_atomic_store(bar_gen, 2, __ATOMIC_RELEASE, __HIP_MEMORY_SCOPE_AGENT);
        } else {
            while (__hip_atomic_load(bar_gen, __ATOMIC_ACQUIRE, __HIP_MEMORY_SCOPE_AGENT) < 2)
                __builtin_amdgcn_s_sleep(8);
        }
    }
    __syncthreads();
    __threadfence();

    // ---- finalize3 (redundant) ----
    if (t < 128) {
        double s = 0.0, q = 0.0;
        for (int i = 0; i < 64; i++) { s += stage3[i * 256 + t]; q += stage3[i * 256 + 128 + t]; }
        double m = s * (1.0 / CNT);
        double v = q * (1.0 / CNT) - m * m;
        double A = (double)g2v[t] / sqrt(v + 1e-5);
        ab3[t] = (float)A;
        ab3[128 + t] = (float)((double)bt2v[t] - m * A);
    }
    __syncthreads();

    // ================= phase C: epilogue, 2 tiles of 16 groups =========
    for (int tile = 0; tile < 2; tile++) {
        int gbase = blk * 32 + tile * 16;          // 16 consecutive groups, same batch
        int b = gbase >> 10, s0 = gbase & 1023;
        for (int j = 0; j < 8; j++) {
            int lin = t + 256 * j;                 // 0..2047
            int sl = lin >> 7, o = lin & 127;
            float a = ab3[o], bb = ab3[128 + o];
            size_t src = (size_t)(gbase + sl) * 128 + o;   // own block's writes -> L2 hit
            float v = (a >= 0.f) ? mxbuf[src] : mnbuf[src];
            sm.C.tile[o][sl] = fmaxf(fmaf(v, a, bb), 0.f);
        }
        __syncthreads();
        for (int j = 0; j < 8; j++) {
            int lin = t + 256 * j;
            int o = lin >> 4, sl = lin & 15;
            out1[((size_t)b * 128 + o) * NP + s0 + sl] = sm.C.tile[o][sl];
        }
        __syncthreads();
    }
}

// =====================================================================
extern "C" void kernel_launch(void* const* d_in, const int* in_sizes, int n_in,
                              void* d_out, int out_size, void* d_ws, size_t ws_size,
                              hipStream_t stream) {
    const float* xyz    = (const float*)d_in[0];
    const float* points = (const float*)d_in[1];
    const float* w0  = (const float*)d_in[2];
    const float* b0  = (const float*)d_in[3];
    const float* g0  = (const float*)d_in[4];
    const float* bt0 = (const float*)d_in[5];
    const float* w1  = (const float*)d_in[6];
    const float* b1  = (const float*)d_in[7];
    const float* g1  = (const float*)d_in[8];
    const float* bt1 = (const float*)d_in[9];
    const float* w2  = (const float*)d_in[10];
    const float* b2  = (const float*)d_in[11];
    const float* g2  = (const float*)d_in[12];
    const float* bt2 = (const float*)d_in[13];

    char* ws = (char*)d_ws;
    // workspace layout (bytes, 256-aligned): total ~94.7 MB
    int*            fidx = (int*)(ws + 0);                       //   64 KB
    int*            idx  = (int*)(ws + 65536);                   //    2 MB
    unsigned short* T    = (unsigned short*)(ws + 2162688);      //  8.4 MB bf16
    unsigned short* h2   = (unsigned short*)(ws + 10551296);     //   67 MB bf16
    float*          mxbuf = (float*)(ws + 77660160);             //  8.4 MB
    float*          mnbuf = (float*)(ws + 86048768);             //  8.4 MB
    double*         stage = (double*)(ws + 94437376);            //  256 KB
    int*            sync_ctr = (int*)(ws + 94701312);            // fused worker barrier
    int*            bar_ctr  = (int*)(ws + 94701316);            // tail grid barrier ctr
    int*            bar_gen  = (int*)(ws + 94701320);            // tail barrier generation
    double* stage1 = stage;
    double* stage2 = stage + 64 * 128;
    double* stage3 = stage + 2 * 64 * 128;
    float* out0 = (float*)d_out;
    float* out1 = out0 + NB * 3 * NP;

    hipMemsetAsync(stage, 0, 262144, stream);        // zero stat slots
    hipMemsetAsync(fidx, 0xFF, NB * NP * 4, stream); // fidx = -1 (spin flags)
    hipMemsetAsync(sync_ctr, 0, 12, stream);         // sync_ctr + bar_ctr + bar_gen

    fused_kernel<<<256, 256, 0, stream>>>(xyz, points, w0, b0, fidx, T, idx,
                                          stage1, out0, sync_ctr);
    tail_kernel<<<TGRID, 256, 0, stream>>>(xyz, T, fidx, idx, w0, b0,
                                           stage1, g0, bt0,
                                           w1, b1, stage2, g1, bt1,
                                           w2, b2, stage3, g2, bt2,
                                           h2, mxbuf, mnbuf, out1,
                                           bar_ctr, bar_gen);
}

// Round 8
// 844.625 us; speedup vs baseline: 1.7108x; 1.2997x over previous
//
#include <hip/hip_runtime.h>
#include <stdint.h>

// Problem constants
#define NB    16
#define NN    4096
#define NP    1024
#define NS    32
#define NGRP  (NB*NP)          // 16384 groups
#define CNT   524288.0         // B*K*S elements per channel for BN stats
#define NWRK  240              // worker blocks (grid 256 = 16 FPS + 240)

typedef short  bf16x8 __attribute__((ext_vector_type(8)));
typedef float  f32x4  __attribute__((ext_vector_type(4)));

// ---------- bf16 helpers (RNE) ----------
__device__ __forceinline__ float bf2f(unsigned short u) {
    return __uint_as_float(((unsigned)u) << 16);
}
__device__ __forceinline__ unsigned short f2bf(float f) {
    unsigned u = __float_as_uint(f);
    unsigned r = u + 0x7fffu + ((u >> 16) & 1u);
    return (unsigned short)(r >> 16);
}
__device__ __forceinline__ bf16x8 as_bf(uint4 u) {
    union { uint4 a; bf16x8 b; } c; c.a = u; return c.b;
}

// u64 max with one DPP step (compare-select). VALU-only.
template <int CTRL, int RM>
__device__ __forceinline__ unsigned long long dppmax(unsigned long long k) {
    int lo = (int)(unsigned)k;
    int hi = (int)(k >> 32);
    int ml = __builtin_amdgcn_update_dpp(lo, lo, CTRL, RM, 0xf, false);
    int mh = __builtin_amdgcn_update_dpp(hi, hi, CTRL, RM, 0xf, false);
    unsigned long long m = ((unsigned long long)(unsigned)mh << 32) | (unsigned)ml;
    return m > k ? m : k;
}

// Redundant per-block BN finalize: AB[o]=A=g/sqrt(v+eps), AB[C+o]=bt-m*A.
// Stats complete+visible via kernel-boundary stream order (no grid sync).
// Bit-identical to the old finalize_kernel (all-double).
__device__ __forceinline__ void finalize_to_lds(const double* __restrict__ stage,
                                                int C, int t,
                                                const float* __restrict__ gamma,
                                                const float* __restrict__ beta,
                                                float* __restrict__ ab) {
    if (t < C) {
        double s = 0.0, q = 0.0;
        for (int i = 0; i < 64; i++) {
            s += stage[i * 2 * C + t];
            q += stage[i * 2 * C + C + t];
        }
        double m = s * (1.0 / CNT);
        double v = q * (1.0 / CNT) - m * m;
        double A = (double)gamma[t] / sqrt(v + 1e-5);
        ab[t] = (float)A;
        ab[C + t] = (float)((double)beta[t] - m * A);
    }
}

// =====================================================================
// FUSED K1 (r5, measured 636us): blocks 0..15 FPS w/ chunked publish;
// blocks 16..255 workers: T transform -> barrier -> s-major group quads.
// r6/r7 lesson: persistent grid-sync tails lose (r6: VGPR spill at
// 4blk/CU; r7: 2blk/CU kills TLP vs 4096-block discrete dispatch, and
// spin barriers misbehave under rocprof replay). Discrete tail + fused
// finalize is the stable optimum.
// =====================================================================
__global__ __launch_bounds__(256, 1) void fused_kernel(const float* __restrict__ xyz,
                                                       const float* __restrict__ points,
                                                       const float* __restrict__ w0,
                                                       const float* __restrict__ b0,
                                                       int* __restrict__ fidx,
                                                       unsigned short* __restrict__ T,
                                                       int* __restrict__ idx,
                                                       double* __restrict__ stage1,
                                                       float* __restrict__ out0,
                                                       int* __restrict__ sync_ctr) {
    __shared__ float4 sxyz4[NN];                    // 64 KB (FPS centroid cache)
    __shared__ unsigned long long red[2][4];        // FPS: parity x wave slots
    __shared__ int fbuf[NP];                        // FPS: result staging (LDS)
    __shared__ int gidx[4][NS];                     // group: per-wave ball idx
    int tid = threadIdx.x;
    int wv = tid >> 6, lane = tid & 63;

    if (blockIdx.x < 16) {
        // ---------------- FPS path (round-0 body + chunked publish) ----
        int b = blockIdx.x;
        const float* xb = xyz + (size_t)b * 3 * NN;
        float px[16], py[16], pz[16], dist[16];
#pragma unroll
        for (int i = 0; i < 16; i++) {
            int n = i * 256 + tid;
            px[i] = xb[n]; py[i] = xb[NN + n]; pz[i] = xb[2 * NN + n];
            sxyz4[n] = make_float4(px[i], py[i], pz[i], 0.f);
            dist[i] = 1e10f;
        }
#pragma unroll
        for (int i = 0; i < 16; i++) {
            asm volatile("" : "+v"(px[i]));
            asm volatile("" : "+v"(py[i]));
            asm volatile("" : "+v"(pz[i]));
        }
        int far = 0;
        if (tid == 0) fbuf[0] = 0;
        __syncthreads();                 // covers sxyz4 + fbuf[0] fill
        for (int t = 0; t < NP; t++) {
            float4 c = sxyz4[far];                   // one ds_read_b128
            float cx = c.x, cy = c.y, cz = c.z;
            float bv = -1.0f; int bi = 0;
#pragma unroll
            for (int i = 0; i < 16; i++) {
                float dx = __fsub_rn(px[i], cx);
                float dy = __fsub_rn(py[i], cy);
                float dz = __fsub_rn(pz[i], cz);
                float d = __fadd_rn(__fadd_rn(__fmul_rn(dx, dx), __fmul_rn(dy, dy)),
                                    __fmul_rn(dz, dz));
                float nd = fminf(dist[i], d);
                dist[i] = nd;
                if (nd > bv) { bv = nd; bi = i; }    // cmp + 2 cndmask
            }
            int n_best = bi * 256 + tid;
            unsigned long long k =
                ((unsigned long long)__float_as_uint(bv) << 32) |
                (unsigned long long)(~(unsigned)n_best);
            k = dppmax<0x111, 0xf>(k);   // row_shr:1
            k = dppmax<0x112, 0xf>(k);   // row_shr:2
            k = dppmax<0x114, 0xf>(k);   // row_shr:4
            k = dppmax<0x118, 0xf>(k);   // row_shr:8
            k = dppmax<0x142, 0xa>(k);   // row_bcast:15
            k = dppmax<0x143, 0xc>(k);   // row_bcast:31
            if ((tid & 63) == 63) red[t & 1][wv] = k;
            // LDS-only barrier: order ds ops, never drain vmcnt.
            asm volatile("s_waitcnt lgkmcnt(0)\n\ts_barrier" ::: "memory");
            // chunked publish: one store instr per 16 iters, fire-and-forget
            if ((t & 15) == 15 && tid < 16) {
                int i = (t - 15) + tid;
                __hip_atomic_store(&fidx[b * NP + i], fbuf[i],
                                   __ATOMIC_RELAXED, __HIP_MEMORY_SCOPE_AGENT);
            }
            ulonglong2 ra = *(ulonglong2*)&red[t & 1][0];
            ulonglong2 rb = *(ulonglong2*)&red[t & 1][2];
            unsigned long long r0 = ra.x, r1 = ra.y, r2 = rb.x, r3 = rb.y;
            if (r1 > r0) r0 = r1;
            if (r3 > r2) r2 = r3;
            if (r2 > r0) r0 = r2;
            far = (int)(~(unsigned)r0);   // low32 = ~n -> n
            if (tid == 0 && t + 1 < NP) fbuf[t + 1] = far;
        }
        return;
    }

    // ---------------- worker path ----------------
    int w = blockIdx.x - 16;     // 0..239
    // ---- phase A: T transform, grid-strided over 65536 points ----
    for (int j = 0; j < 2; j++) {
        int gid = w * 256 + tid + j * (NWRK * 256);   // b*4096 + n
        if (gid < NB * NN) {
            int b = gid >> 12, n = gid & (NN - 1);
            const float* xb = xyz + (size_t)b * 3 * NN;
            const float* pb = points + (size_t)b * 64 * NN;
            float acc[64];
#pragma unroll
            for (int o = 0; o < 64; o++) acc[o] = 0.f;
            for (int c = 0; c < 67; c++) {
                float v = (c < 3) ? xb[c * NN + n] : pb[(c - 3) * NN + n];
#pragma unroll
                for (int o = 0; o < 64; o++) acc[o] = fmaf(v, w0[o * 67 + c], acc[o]);
            }
            unsigned short* dst = T + (size_t)gid * 64;
            for (int oo = 0; oo < 64; oo += 8) {
                union { unsigned short u[8]; uint4 v; } r;
#pragma unroll
                for (int jj = 0; jj < 8; jj++) r.u[jj] = f2bf(acc[oo + jj]);
                *(uint4*)&dst[oo] = r.v;
            }
        }
    }
    // ---- phase B: worker barrier (T fully visible before any group reads) ----
    __syncthreads();
    __threadfence();             // release T stores
    if (tid == 0) {
        __hip_atomic_fetch_add(sync_ctr, 1, __ATOMIC_ACQ_REL, __HIP_MEMORY_SCOPE_AGENT);
        while (__hip_atomic_load(sync_ctr, __ATOMIC_ACQUIRE, __HIP_MEMORY_SCOPE_AGENT) < NWRK)
            __builtin_amdgcn_s_sleep(32);
    }
    __syncthreads();
    __threadfence();             // acquire side

    // ---- phase C: s-major quad order; spin per-wave on fidx[g] ----
    {
        int b = w & 15;          // fixed batch per worker
        int r = w >> 4;          // k-lane 0..14
        const float* xb = xyz + (size_t)b * 3 * NN;
        const unsigned short* Tb = T + (size_t)b * NN * 64;
        for (int kk = r; kk < 256; kk += 15) {
            int s = (kk << 2) + wv;                  // monotone in loop
            int g = (b << 10) + s;
            int fid;
            if (lane == 0) {
                fid = __hip_atomic_load(&fidx[g], __ATOMIC_RELAXED, __HIP_MEMORY_SCOPE_AGENT);
                while (fid < 0) {
                    __builtin_amdgcn_s_sleep(16);
                    fid = __hip_atomic_load(&fidx[g], __ATOMIC_RELAXED, __HIP_MEMORY_SCOPE_AGENT);
                }
            }
            fid = __shfl(fid, 0);
            float cx = xb[fid], cy = xb[NN + fid], cz = xb[2 * NN + fid];
            if (lane < 3) {
                float v = (lane == 0) ? cx : ((lane == 1) ? cy : cz);
                out0[((size_t)b * 3 + lane) * NP + s] = v;
            }
            float sa = __fadd_rn(__fadd_rn(__fmul_rn(cx, cx), __fmul_rn(cy, cy)),
                                 __fmul_rn(cz, cz));
            int* out = idx + (size_t)g * NS;
            int total = 0; int first = 0;
            for (int ci = 0; ci < NN / 64; ci++) {
                int n = ci * 64 + lane;
                float x = xb[n], y = xb[NN + n], z = xb[2 * NN + n];
                float sb = __fadd_rn(__fadd_rn(__fmul_rn(x, x), __fmul_rn(y, y)),
                                     __fmul_rn(z, z));
                float dot = __fadd_rn(__fadd_rn(__fmul_rn(x, cx), __fmul_rn(y, cy)),
                                      __fmul_rn(z, cz));
                float sqr = __fsub_rn(__fadd_rn(sa, sb), __fmul_rn(2.0f, dot));
                bool pred = !(sqr > 0.04f);
                unsigned long long mask = __ballot(pred);
                if (mask) {
                    if (total == 0) first = ci * 64 + (int)__builtin_ctzll(mask);
                    int pos = total + (int)__popcll(mask & ((1ull << lane) - 1ull));
                    if (pred && pos < NS) { out[pos] = n; gidx[wv][pos] = n; }
                    total += (int)__popcll(mask);
                    if (total >= NS) break;
                }
            }
            if (total < NS) {
                if (lane >= total && lane < NS) { out[lane] = first; gidx[wv][lane] = first; }
            }
            // ---- BN1 stats: lane = channel o ----
            int o = lane;
            float uo = fmaf(w0[o * 67 + 2], cz, fmaf(w0[o * 67 + 1], cy, w0[o * 67] * cx));
            float bo = b0[o];
            float s1 = 0.f, s2 = 0.f;
            for (int k = 0; k < NS; k++) {
                int n = gidx[wv][k];
                float tv = bf2f(Tb[(size_t)n * 64 + o]);
                float h = tv - uo + bo;
                s1 += h; s2 = fmaf(h, h, s2);
            }
            int slot = g & 63;
            atomicAdd(&stage1[slot * 128 + o], (double)s1);
            atomicAdd(&stage1[slot * 128 + 64 + o], (double)s2);
        }
    }
}

// =====================================================================
// K5: layer2 MFMA (discrete, r5 structure) + fused finalize1.
// Block = 4 waves = 4 groups; 16 MFMA/wave.
// =====================================================================
__global__ __launch_bounds__(256) void layer2_kernel(const float* __restrict__ xyz,
                                                     const unsigned short* __restrict__ T,
                                                     const int* __restrict__ fidx,
                                                     const int* __restrict__ idx,
                                                     const float* __restrict__ w0,
                                                     const float* __restrict__ b0,
                                                     const double* __restrict__ stage1,
                                                     const float* __restrict__ g0v,
                                                     const float* __restrict__ bt0v,
                                                     const float* __restrict__ w1,
                                                     const float* __restrict__ b1,
                                                     unsigned short* __restrict__ h2,
                                                     double* __restrict__ stage2) {
    __shared__ __attribute__((aligned(16))) unsigned short w1s[64][72];     // [o2][o]
    __shared__ __attribute__((aligned(16))) unsigned short h1s[4][32][72];  // [wv][k][o]
    __shared__ float psum[64], psq[64];
    __shared__ float ab1[128];
    int t = threadIdx.x, wv = t >> 6, lane = t & 63;
    int quad = lane >> 4, col = lane & 15;
    int g = blockIdx.x * 4 + wv;
    int b = g >> 10;
    for (int lin = t; lin < 4096; lin += 256)
        w1s[lin >> 6][lin & 63] = f2bf(w1[lin]);
    finalize_to_lds(stage1, 64, t, g0v, bt0v, ab1);   // redundant per block
    if (t < 64) { psum[t] = 0.f; psq[t] = 0.f; }
    __syncthreads();                                  // ab1 visible
    {   // phase1: rebuild normalized h1 (bf16) into LDS [k][o], lane = o
        int fid = fidx[g];
        const float* xb = xyz + (size_t)b * 3 * NN;
        float cx = xb[fid], cy = xb[NN + fid], cz = xb[2 * NN + fid];
        int o = lane;
        float uo = fmaf(w0[o * 67 + 2], cz, fmaf(w0[o * 67 + 1], cy, w0[o * 67] * cx));
        float bo = b0[o];
        float a1 = ab1[o], bb1 = ab1[64 + o];
        const int* gi = idx + (size_t)g * NS;
        const unsigned short* Tb = T + (size_t)b * NN * 64;
        for (int k = 0; k < NS; k++) {
            int n = gi[k];
            float tv = bf2f(Tb[(size_t)n * 64 + o]);
            float h = tv - uo + bo;
            float hn = fmaxf(fmaf(h, a1, bb1), 0.f);
            h1s[wv][k][o] = f2bf(hn);
        }
    }
    __syncthreads();
    // ---- MFMA: 2 mt x 4 nt x 2 ks ----
    f32x4 acc[2][4];
#pragma unroll
    for (int i = 0; i < 2; i++)
#pragma unroll
        for (int j = 0; j < 4; j++) acc[i][j] = (f32x4){0.f, 0.f, 0.f, 0.f};
#pragma unroll
    for (int ks = 0; ks < 2; ks++) {
        bf16x8 a0 = as_bf(*(const uint4*)&h1s[wv][col][ks * 32 + quad * 8]);
        bf16x8 a1f = as_bf(*(const uint4*)&h1s[wv][16 + col][ks * 32 + quad * 8]);
#pragma unroll
        for (int nt = 0; nt < 4; nt++) {
            bf16x8 bf = as_bf(*(const uint4*)&w1s[nt * 16 + col][ks * 32 + quad * 8]);
            acc[0][nt] = __builtin_amdgcn_mfma_f32_16x16x32_bf16(a0, bf, acc[0][nt], 0, 0, 0);
            acc[1][nt] = __builtin_amdgcn_mfma_f32_16x16x32_bf16(a1f, bf, acc[1][nt], 0, 0, 0);
        }
    }
    // ---- epilogue: + b1, BN2 stats, restage C (bf16) into h1s ----
    float s1[4], s2[4];
#pragma unroll
    for (int nt = 0; nt < 4; nt++) {
        float bb = b1[nt * 16 + col];
        s1[nt] = 0.f; s2[nt] = 0.f;
#pragma unroll
        for (int mt = 0; mt < 2; mt++)
#pragma unroll
            for (int r = 0; r < 4; r++) {
                float v = acc[mt][nt][r] + bb;
                s1[nt] += v; s2[nt] = fmaf(v, v, s2[nt]);
                h1s[wv][mt * 16 + quad * 4 + r][nt * 16 + col] = f2bf(v);
            }
        s1[nt] += __shfl_xor(s1[nt], 16); s1[nt] += __shfl_xor(s1[nt], 32);
        s2[nt] += __shfl_xor(s2[nt], 16); s2[nt] += __shfl_xor(s2[nt], 32);
        if (quad == 0) {
            atomicAdd(&psum[nt * 16 + col], s1[nt]);
            atomicAdd(&psq[nt * 16 + col], s2[nt]);
        }
    }
    // ---- h2 global store: coalesced uint4 rows from LDS ----
#pragma unroll
    for (int r = 0; r < 4; r++) {
        int lin = lane + 64 * r;
        int row = lin >> 3, c = lin & 7;
        uint4 v = *(const uint4*)&h1s[wv][row][c * 8];
        *(uint4*)&h2[((size_t)g * NS + row) * 64 + c * 8] = v;
    }
    __syncthreads();
    if (t < 64) {
        int slot = blockIdx.x & 63;
        atomicAdd(&stage2[slot * 128 + t], (double)psum[t]);
        atomicAdd(&stage2[slot * 128 + 64 + t], (double)psq[t]);
    }
}

// =====================================================================
// K7: layer3 MFMA (discrete, r5 structure) + fused finalize2.
// 32 MFMA/wave; emits BN3 partials + per-(g,o3) max/min.
// =====================================================================
__global__ __launch_bounds__(256) void layer3_kernel(const unsigned short* __restrict__ h2,
                                                     const double* __restrict__ stage2,
                                                     const float* __restrict__ g1v,
                                                     const float* __restrict__ bt1v,
                                                     const float* __restrict__ w2,
                                                     const float* __restrict__ b2,
                                                     double* __restrict__ stage3,
                                                     float* __restrict__ mxbuf,
                                                     float* __restrict__ mnbuf) {
    __shared__ __attribute__((aligned(16))) unsigned short w2s[128][72];    // [o3][o2]
    __shared__ __attribute__((aligned(16))) unsigned short h2s[4][32][72];  // [wv][k][o2]
    __shared__ float psum[128], psq[128];
    __shared__ float ab2[128];
    int t = threadIdx.x, wv = t >> 6, lane = t & 63;
    int quad = lane >> 4, col = lane & 15;
    int g = blockIdx.x * 4 + wv;
    for (int lin = t; lin < 8192; lin += 256)
        w2s[lin >> 6][lin & 63] = f2bf(w2[lin]);
    finalize_to_lds(stage2, 64, t, g1v, bt1v, ab2);   // redundant per block
    if (t < 128) { psum[t] = 0.f; psq[t] = 0.f; }
    __syncthreads();                                  // ab2 visible
    {   // phase1: h2 -> BN2+relu -> LDS bf16. lane owns channels c*8..c*8+7
        int c = lane & 7;
        float a2v[8], bb2v[8];
#pragma unroll
        for (int j = 0; j < 8; j++) {
            a2v[j] = ab2[c * 8 + j];
            bb2v[j] = ab2[64 + c * 8 + j];
        }
        const unsigned short* hg = h2 + (size_t)g * NS * 64;
#pragma unroll
        for (int r = 0; r < 4; r++) {
            int row = (lane >> 3) + 8 * r;
            union { uint4 v; unsigned short u[8]; } in, outp;
            in.v = *(const uint4*)&hg[row * 64 + c * 8];
#pragma unroll
            for (int j = 0; j < 8; j++) {
                float f = bf2f(in.u[j]);
                outp.u[j] = f2bf(fmaxf(fmaf(f, a2v[j], bb2v[j]), 0.f));
            }
            *(uint4*)&h2s[wv][row][c * 8] = outp.v;
        }
    }
    __syncthreads();
    // ---- MFMA: 2 mt x 8 nt x 2 ks ----
    f32x4 acc[2][8];
#pragma unroll
    for (int i = 0; i < 2; i++)
#pragma unroll
        for (int j = 0; j < 8; j++) acc[i][j] = (f32x4){0.f, 0.f, 0.f, 0.f};
#pragma unroll
    for (int ks = 0; ks < 2; ks++) {
        bf16x8 a0 = as_bf(*(const uint4*)&h2s[wv][col][ks * 32 + quad * 8]);
        bf16x8 a1f = as_bf(*(const uint4*)&h2s[wv][16 + col][ks * 32 + quad * 8]);
#pragma unroll
        for (int nt = 0; nt < 8; nt++) {
            bf16x8 bf = as_bf(*(const uint4*)&w2s[nt * 16 + col][ks * 32 + quad * 8]);
            acc[0][nt] = __builtin_amdgcn_mfma_f32_16x16x32_bf16(a0, bf, acc[0][nt], 0, 0, 0);
            acc[1][nt] = __builtin_amdgcn_mfma_f32_16x16x32_bf16(a1f, bf, acc[1][nt], 0, 0, 0);
        }
    }
    // ---- epilogue: + b2, BN3 stats + per-o3 max/min over k ----
#pragma unroll
    for (int nt = 0; nt < 8; nt++) {
        float bb = b2[nt * 16 + col];
        float s1 = 0.f, s2 = 0.f, mx = -1e30f, mn = 1e30f;
#pragma unroll
        for (int mt = 0; mt < 2; mt++)
#pragma unroll
            for (int r = 0; r < 4; r++) {
                float v = acc[mt][nt][r] + bb;
                s1 += v; s2 = fmaf(v, v, s2);
                mx = fmaxf(mx, v); mn = fminf(mn, v);
            }
        s1 += __shfl_xor(s1, 16); s1 += __shfl_xor(s1, 32);
        s2 += __shfl_xor(s2, 16); s2 += __shfl_xor(s2, 32);
        mx = fmaxf(mx, __shfl_xor(mx, 16)); mx = fmaxf(mx, __shfl_xor(mx, 32));
        mn = fminf(mn, __shfl_xor(mn, 16)); mn = fminf(mn, __shfl_xor(mn, 32));
        if (quad == 0) {
            atomicAdd(&psum[nt * 16 + col], s1);
            atomicAdd(&psq[nt * 16 + col], s2);
            mxbuf[(size_t)g * 128 + nt * 16 + col] = mx;
            mnbuf[(size_t)g * 128 + nt * 16 + col] = mn;
        }
    }
    __syncthreads();
    if (t < 128) {
        int slot = blockIdx.x & 63;
        atomicAdd(&stage3[slot * 256 + t], (double)psum[t]);
        atomicAdd(&stage3[slot * 256 + 128 + t], (double)psq[t]);
    }
}

// =====================================================================
// K9: epilogue (discrete, r5 structure) + fused finalize3.
// out1[b][o][s] = relu(a3*sel+b3), sel = a3>=0?max:min.
// =====================================================================
__global__ __launch_bounds__(256) void epilogue_kernel(const float* __restrict__ mxbuf,
                                                       const float* __restrict__ mnbuf,
                                                       const double* __restrict__ stage3,
                                                       const float* __restrict__ g2v,
                                                       const float* __restrict__ bt2v,
                                                       float* __restrict__ out1) {
    __shared__ float tile[32][65];
    __shared__ float ab3[256];
    int blk = blockIdx.x;
    int b = blk >> 6; int rem = blk & 63;
    int o0 = (rem >> 4) * 32; int s0 = (rem & 15) * 64;
    int t = threadIdx.x;
    finalize_to_lds(stage3, 128, t, g2v, bt2v, ab3);  // redundant per block
    __syncthreads();                                  // ab3 visible
#pragma unroll
    for (int j = 0; j < 8; j++) {
        int lin = t + 256 * j;
        int sl = lin >> 5, ol = lin & 31;
        int o = o0 + ol;
        float a = ab3[o], bb = ab3[128 + o];
        size_t src = ((size_t)b * NP + s0 + sl) * 128 + o;
        float v = (a >= 0.f) ? mxbuf[src] : mnbuf[src];
        tile[ol][sl] = fmaxf(fmaf(v, a, bb), 0.f);
    }
    __syncthreads();
#pragma unroll
    for (int j = 0; j < 8; j++) {
        int lin = t + 256 * j;
        int ol = lin >> 6, sl = lin & 63;
        out1[((size_t)b * 128 + o0 + ol) * NP + s0 + sl] = tile[ol][sl];
    }
}

// =====================================================================
extern "C" void kernel_launch(void* const* d_in, const int* in_sizes, int n_in,
                              void* d_out, int out_size, void* d_ws, size_t ws_size,
                              hipStream_t stream) {
    const float* xyz    = (const float*)d_in[0];
    const float* points = (const float*)d_in[1];
    const float* w0  = (const float*)d_in[2];
    const float* b0  = (const float*)d_in[3];
    const float* g0  = (const float*)d_in[4];
    const float* bt0 = (const float*)d_in[5];
    const float* w1  = (const float*)d_in[6];
    const float* b1  = (const float*)d_in[7];
    const float* g1  = (const float*)d_in[8];
    const float* bt1 = (const float*)d_in[9];
    const float* w2  = (const float*)d_in[10];
    const float* b2  = (const float*)d_in[11];
    const float* g2  = (const float*)d_in[12];
    const float* bt2 = (const float*)d_in[13];

    char* ws = (char*)d_ws;
    // workspace layout (bytes, 256-aligned): total ~94.7 MB
    int*            fidx = (int*)(ws + 0);                       //   64 KB
    int*            idx  = (int*)(ws + 65536);                   //    2 MB
    unsigned short* T    = (unsigned short*)(ws + 2162688);      //  8.4 MB bf16
    unsigned short* h2   = (unsigned short*)(ws + 10551296);     //   67 MB bf16
    float*          mxbuf = (float*)(ws + 77660160);             //  8.4 MB
    float*          mnbuf = (float*)(ws + 86048768);             //  8.4 MB
    double*         stage = (double*)(ws + 94437376);            //  256 KB
    int*            sync_ctr = (int*)(ws + 94701312);            // fused worker barrier
    double* stage1 = stage;
    double* stage2 = stage + 64 * 128;
    double* stage3 = stage + 2 * 64 * 128;
    float* out0 = (float*)d_out;
    float* out1 = out0 + NB * 3 * NP;

    hipMemsetAsync(stage, 0, 262144, stream);        // zero stat slots
    hipMemsetAsync(fidx, 0xFF, NB * NP * 4, stream); // fidx = -1 (spin flags)
    hipMemsetAsync(sync_ctr, 0, 4, stream);          // worker barrier ctr

    fused_kernel<<<256, 256, 0, stream>>>(xyz, points, w0, b0, fidx, T, idx,
                                          stage1, out0, sync_ctr);
    layer2_kernel<<<NGRP / 4, 256, 0, stream>>>(xyz, T, fidx, idx, w0, b0,
                                                stage1, g0, bt0,
                                                w1, b1, h2, stage2);
    layer3_kernel<<<NGRP / 4, 256, 0, stream>>>(h2, stage2, g1, bt1,
                                                w2, b2, stage3, mxbuf, mnbuf);
    epilogue_kernel<<<1024, 256, 0, stream>>>(mxbuf, mnbuf, stage3, g2, bt2, out1);
}

// Round 9
// 825.663 us; speedup vs baseline: 1.7501x; 1.0230x over previous
//
#include <hip/hip_runtime.h>
#include <stdint.h>

// Problem constants
#define NB    16
#define NN    4096
#define NP    1024
#define NS    32
#define NGRP  (NB*NP)          // 16384 groups
#define CNT   524288.0         // B*K*S elements per channel for BN stats
#define NWRK  240              // worker blocks (grid 256 = 16 FPS + 240)

typedef short  bf16x8 __attribute__((ext_vector_type(8)));
typedef float  f32x4  __attribute__((ext_vector_type(4)));

// ---------- bf16 helpers (RNE) ----------
__device__ __forceinline__ float bf2f(unsigned short u) {
    return __uint_as_float(((unsigned)u) << 16);
}
__device__ __forceinline__ unsigned short f2bf(float f) {
    unsigned u = __float_as_uint(f);
    unsigned r = u + 0x7fffu + ((u >> 16) & 1u);
    return (unsigned short)(r >> 16);
}
__device__ __forceinline__ bf16x8 as_bf(uint4 u) {
    union { uint4 a; bf16x8 b; } c; c.a = u; return c.b;
}

// u64 max with one DPP step (compare-select). VALU-only.
template <int CTRL, int RM>
__device__ __forceinline__ unsigned long long dppmax(unsigned long long k) {
    int lo = (int)(unsigned)k;
    int hi = (int)(k >> 32);
    int ml = __builtin_amdgcn_update_dpp(lo, lo, CTRL, RM, 0xf, false);
    int mh = __builtin_amdgcn_update_dpp(hi, hi, CTRL, RM, 0xf, false);
    unsigned long long m = ((unsigned long long)(unsigned)mh << 32) | (unsigned)ml;
    return m > k ? m : k;
}

// =====================================================================
// FUSED K1 (r5, measured 636us; restored verbatim): blocks 0..15 FPS
// with chunked fire-and-forget publish; blocks 16..255 workers:
// T transform -> worker barrier -> s-major group quads (monotone
// availability, batch-local reads).
// Session evidence: FPS loop is chain-latency-bound (r1 pk-math flat,
// r2 coord-carry -42%); per-iter publish must avoid vmcnt drain in the
// barrier (r3: +152us via __syncthreads) -> lgkm-only barrier + 16-iter
// chunked publish (r5). Persistent/fused tails all lost (r6 spill,
// r7 TLP loss, r8 redundant-finalize cost) -> discrete tail below.
// =====================================================================
__global__ __launch_bounds__(256, 1) void fused_kernel(const float* __restrict__ xyz,
                                                       const float* __restrict__ points,
                                                       const float* __restrict__ w0,
                                                       const float* __restrict__ b0,
                                                       int* __restrict__ fidx,
                                                       unsigned short* __restrict__ T,
                                                       int* __restrict__ idx,
                                                       double* __restrict__ stage1,
                                                       float* __restrict__ out0,
                                                       int* __restrict__ sync_ctr) {
    __shared__ float4 sxyz4[NN];                    // 64 KB (FPS centroid cache)
    __shared__ unsigned long long red[2][4];        // FPS: parity x wave slots
    __shared__ int fbuf[NP];                        // FPS: result staging (LDS)
    __shared__ int gidx[4][NS];                     // group: per-wave ball idx
    int tid = threadIdx.x;
    int wv = tid >> 6, lane = tid & 63;

    if (blockIdx.x < 16) {
        // ---------------- FPS path (round-0 body + chunked publish) ----
        int b = blockIdx.x;
        const float* xb = xyz + (size_t)b * 3 * NN;
        float px[16], py[16], pz[16], dist[16];
#pragma unroll
        for (int i = 0; i < 16; i++) {
            int n = i * 256 + tid;
            px[i] = xb[n]; py[i] = xb[NN + n]; pz[i] = xb[2 * NN + n];
            sxyz4[n] = make_float4(px[i], py[i], pz[i], 0.f);
            dist[i] = 1e10f;
        }
#pragma unroll
        for (int i = 0; i < 16; i++) {
            asm volatile("" : "+v"(px[i]));
            asm volatile("" : "+v"(py[i]));
            asm volatile("" : "+v"(pz[i]));
        }
        int far = 0;
        if (tid == 0) fbuf[0] = 0;
        __syncthreads();                 // covers sxyz4 + fbuf[0] fill
        for (int t = 0; t < NP; t++) {
            float4 c = sxyz4[far];                   // one ds_read_b128
            float cx = c.x, cy = c.y, cz = c.z;
            float bv = -1.0f; int bi = 0;
#pragma unroll
            for (int i = 0; i < 16; i++) {
                float dx = __fsub_rn(px[i], cx);
                float dy = __fsub_rn(py[i], cy);
                float dz = __fsub_rn(pz[i], cz);
                float d = __fadd_rn(__fadd_rn(__fmul_rn(dx, dx), __fmul_rn(dy, dy)),
                                    __fmul_rn(dz, dz));
                float nd = fminf(dist[i], d);
                dist[i] = nd;
                if (nd > bv) { bv = nd; bi = i; }    // cmp + 2 cndmask
            }
            int n_best = bi * 256 + tid;
            unsigned long long k =
                ((unsigned long long)__float_as_uint(bv) << 32) |
                (unsigned long long)(~(unsigned)n_best);
            k = dppmax<0x111, 0xf>(k);   // row_shr:1
            k = dppmax<0x112, 0xf>(k);   // row_shr:2
            k = dppmax<0x114, 0xf>(k);   // row_shr:4
            k = dppmax<0x118, 0xf>(k);   // row_shr:8
            k = dppmax<0x142, 0xa>(k);   // row_bcast:15
            k = dppmax<0x143, 0xc>(k);   // row_bcast:31
            if ((tid & 63) == 63) red[t & 1][wv] = k;
            // LDS-only barrier: order ds ops, never drain vmcnt.
            asm volatile("s_waitcnt lgkmcnt(0)\n\ts_barrier" ::: "memory");
            // chunked publish: one store instr per 16 iters, fire-and-forget
            if ((t & 15) == 15 && tid < 16) {
                int i = (t - 15) + tid;
                __hip_atomic_store(&fidx[b * NP + i], fbuf[i],
                                   __ATOMIC_RELAXED, __HIP_MEMORY_SCOPE_AGENT);
            }
            ulonglong2 ra = *(ulonglong2*)&red[t & 1][0];
            ulonglong2 rb = *(ulonglong2*)&red[t & 1][2];
            unsigned long long r0 = ra.x, r1 = ra.y, r2 = rb.x, r3 = rb.y;
            if (r1 > r0) r0 = r1;
            if (r3 > r2) r2 = r3;
            if (r2 > r0) r0 = r2;
            far = (int)(~(unsigned)r0);   // low32 = ~n -> n
            if (tid == 0 && t + 1 < NP) fbuf[t + 1] = far;
        }
        return;
    }

    // ---------------- worker path ----------------
    int w = blockIdx.x - 16;     // 0..239
    // ---- phase A: T transform, grid-strided over 65536 points ----
    for (int j = 0; j < 2; j++) {
        int gid = w * 256 + tid + j * (NWRK * 256);   // b*4096 + n
        if (gid < NB * NN) {
            int b = gid >> 12, n = gid & (NN - 1);
            const float* xb = xyz + (size_t)b * 3 * NN;
            const float* pb = points + (size_t)b * 64 * NN;
            float acc[64];
#pragma unroll
            for (int o = 0; o < 64; o++) acc[o] = 0.f;
            for (int c = 0; c < 67; c++) {
                float v = (c < 3) ? xb[c * NN + n] : pb[(c - 3) * NN + n];
#pragma unroll
                for (int o = 0; o < 64; o++) acc[o] = fmaf(v, w0[o * 67 + c], acc[o]);
            }
            unsigned short* dst = T + (size_t)gid * 64;
            for (int oo = 0; oo < 64; oo += 8) {
                union { unsigned short u[8]; uint4 v; } r;
#pragma unroll
                for (int jj = 0; jj < 8; jj++) r.u[jj] = f2bf(acc[oo + jj]);
                *(uint4*)&dst[oo] = r.v;
            }
        }
    }
    // ---- phase B: worker barrier (T fully visible before any group reads) ----
    __syncthreads();
    __threadfence();             // release T stores
    if (tid == 0) {
        __hip_atomic_fetch_add(sync_ctr, 1, __ATOMIC_ACQ_REL, __HIP_MEMORY_SCOPE_AGENT);
        while (__hip_atomic_load(sync_ctr, __ATOMIC_ACQUIRE, __HIP_MEMORY_SCOPE_AGENT) < NWRK)
            __builtin_amdgcn_s_sleep(32);
    }
    __syncthreads();
    __threadfence();             // acquire side

    // ---- phase C: s-major quad order; spin per-wave on fidx[g] ----
    {
        int b = w & 15;          // fixed batch per worker
        int r = w >> 4;          // k-lane 0..14
        const float* xb = xyz + (size_t)b * 3 * NN;
        const unsigned short* Tb = T + (size_t)b * NN * 64;
        for (int kk = r; kk < 256; kk += 15) {
            int s = (kk << 2) + wv;                  // monotone in loop
            int g = (b << 10) + s;
            int fid;
            if (lane == 0) {
                fid = __hip_atomic_load(&fidx[g], __ATOMIC_RELAXED, __HIP_MEMORY_SCOPE_AGENT);
                while (fid < 0) {
                    __builtin_amdgcn_s_sleep(16);
                    fid = __hip_atomic_load(&fidx[g], __ATOMIC_RELAXED, __HIP_MEMORY_SCOPE_AGENT);
                }
            }
            fid = __shfl(fid, 0);
            float cx = xb[fid], cy = xb[NN + fid], cz = xb[2 * NN + fid];
            if (lane < 3) {
                float v = (lane == 0) ? cx : ((lane == 1) ? cy : cz);
                out0[((size_t)b * 3 + lane) * NP + s] = v;
            }
            float sa = __fadd_rn(__fadd_rn(__fmul_rn(cx, cx), __fmul_rn(cy, cy)),
                                 __fmul_rn(cz, cz));
            int* out = idx + (size_t)g * NS;
            int total = 0; int first = 0;
            for (int ci = 0; ci < NN / 64; ci++) {
                int n = ci * 64 + lane;
                float x = xb[n], y = xb[NN + n], z = xb[2 * NN + n];
                float sb = __fadd_rn(__fadd_rn(__fmul_rn(x, x), __fmul_rn(y, y)),
                                     __fmul_rn(z, z));
                float dot = __fadd_rn(__fadd_rn(__fmul_rn(x, cx), __fmul_rn(y, cy)),
                                      __fmul_rn(z, cz));
                float sqr = __fsub_rn(__fadd_rn(sa, sb), __fmul_rn(2.0f, dot));
                bool pred = !(sqr > 0.04f);
                unsigned long long mask = __ballot(pred);
                if (mask) {
                    if (total == 0) first = ci * 64 + (int)__builtin_ctzll(mask);
                    int pos = total + (int)__popcll(mask & ((1ull << lane) - 1ull));
                    if (pred && pos < NS) { out[pos] = n; gidx[wv][pos] = n; }
                    total += (int)__popcll(mask);
                    if (total >= NS) break;
                }
            }
            if (total < NS) {
                if (lane >= total && lane < NS) { out[lane] = first; gidx[wv][lane] = first; }
            }
            // ---- BN1 stats: lane = channel o ----
            int o = lane;
            float uo = fmaf(w0[o * 67 + 2], cz, fmaf(w0[o * 67 + 1], cy, w0[o * 67] * cx));
            float bo = b0[o];
            float s1 = 0.f, s2 = 0.f;
            for (int k = 0; k < NS; k++) {
                int n = gidx[wv][k];
                float tv = bf2f(Tb[(size_t)n * 64 + o]);
                float h = tv - uo + bo;
                s1 += h; s2 = fmaf(h, h, s2);
            }
            int slot = g & 63;
            atomicAdd(&stage1[slot * 128 + o], (double)s1);
            atomicAdd(&stage1[slot * 128 + 64 + o], (double)s2);
        }
    }
}

// =====================================================================
// Finalize BN stats: AB[o]=A=g/sqrt(v+eps), AB[C+o]=B=bt-m*A
// (discrete 1-block kernel — r8 showed fusing this into 4096 consumer
// blocks costs +19us of redundant per-block serial reduction)
// =====================================================================
__global__ void finalize_kernel(const double* __restrict__ stage, int C,
                                const float* __restrict__ gamma,
                                const float* __restrict__ beta,
                                float* __restrict__ AB) {
    int o = threadIdx.x;
    double s = 0.0, q = 0.0;
    for (int i = 0; i < 64; i++) {
        s += stage[i * 2 * C + o];
        q += stage[i * 2 * C + C + o];
    }
    double m = s * (1.0 / CNT);
    double v = q * (1.0 / CNT) - m * m;
    double A = (double)gamma[o] / sqrt(v + 1e-5);
    AB[o] = (float)A;
    AB[C + o] = (float)((double)beta[o] - m * A);
}

// =====================================================================
// K5: layer2 MFMA. Block = 4 waves = 4 groups. Per group:
// C[k=32][o2=64] = A[k][o=64] x B[o][o2], 16x16x32 bf16 MFMA:
// 2 m-tiles x 4 n-tiles x 2 K-steps = 16 MFMA/wave.
// =====================================================================
__global__ __launch_bounds__(256) void layer2_kernel(const float* __restrict__ xyz,
                                                     const unsigned short* __restrict__ T,
                                                     const int* __restrict__ fidx,
                                                     const int* __restrict__ idx,
                                                     const float* __restrict__ w0,
                                                     const float* __restrict__ b0,
                                                     const float* __restrict__ AB1,
                                                     const float* __restrict__ w1,
                                                     const float* __restrict__ b1,
                                                     unsigned short* __restrict__ h2,
                                                     double* __restrict__ stage2) {
    __shared__ __attribute__((aligned(16))) unsigned short w1s[64][72];     // [o2][o]
    __shared__ __attribute__((aligned(16))) unsigned short h1s[4][32][72];  // [wv][k][o]
    __shared__ float psum[64], psq[64];
    int t = threadIdx.x, wv = t >> 6, lane = t & 63;
    int quad = lane >> 4, col = lane & 15;
    int g = blockIdx.x * 4 + wv;
    int b = g >> 10;
    for (int lin = t; lin < 4096; lin += 256)
        w1s[lin >> 6][lin & 63] = f2bf(w1[lin]);
    if (t < 64) { psum[t] = 0.f; psq[t] = 0.f; }
    {   // phase1: rebuild normalized h1 (bf16) into LDS [k][o], lane = o
        int fid = fidx[g];
        const float* xb = xyz + (size_t)b * 3 * NN;
        float cx = xb[fid], cy = xb[NN + fid], cz = xb[2 * NN + fid];
        int o = lane;
        float uo = fmaf(w0[o * 67 + 2], cz, fmaf(w0[o * 67 + 1], cy, w0[o * 67] * cx));
        float bo = b0[o];
        float a1 = AB1[o], bb1 = AB1[64 + o];
        const int* gi = idx + (size_t)g * NS;
        const unsigned short* Tb = T + (size_t)b * NN * 64;
        for (int k = 0; k < NS; k++) {
            int n = gi[k];
            float tv = bf2f(Tb[(size_t)n * 64 + o]);
            float h = tv - uo + bo;
            float hn = fmaxf(fmaf(h, a1, bb1), 0.f);
            h1s[wv][k][o] = f2bf(hn);
        }
    }
    __syncthreads();
    // ---- MFMA: 2 mt x 4 nt x 2 ks ----
    f32x4 acc[2][4];
#pragma unroll
    for (int i = 0; i < 2; i++)
#pragma unroll
        for (int j = 0; j < 4; j++) acc[i][j] = (f32x4){0.f, 0.f, 0.f, 0.f};
#pragma unroll
    for (int ks = 0; ks < 2; ks++) {
        bf16x8 a0 = as_bf(*(const uint4*)&h1s[wv][col][ks * 32 + quad * 8]);
        bf16x8 a1f = as_bf(*(const uint4*)&h1s[wv][16 + col][ks * 32 + quad * 8]);
#pragma unroll
        for (int nt = 0; nt < 4; nt++) {
            bf16x8 bf = as_bf(*(const uint4*)&w1s[nt * 16 + col][ks * 32 + quad * 8]);
            acc[0][nt] = __builtin_amdgcn_mfma_f32_16x16x32_bf16(a0, bf, acc[0][nt], 0, 0, 0);
            acc[1][nt] = __builtin_amdgcn_mfma_f32_16x16x32_bf16(a1f, bf, acc[1][nt], 0, 0, 0);
        }
    }
    // ---- epilogue: + b1, BN2 stats, restage C (bf16) into h1s ----
    float s1[4], s2[4];
#pragma unroll
    for (int nt = 0; nt < 4; nt++) {
        float bb = b1[nt * 16 + col];
        s1[nt] = 0.f; s2[nt] = 0.f;
#pragma unroll
        for (int mt = 0; mt < 2; mt++)
#pragma unroll
            for (int r = 0; r < 4; r++) {
                float v = acc[mt][nt][r] + bb;
                s1[nt] += v; s2[nt] = fmaf(v, v, s2[nt]);
                h1s[wv][mt * 16 + quad * 4 + r][nt * 16 + col] = f2bf(v);
            }
        s1[nt] += __shfl_xor(s1[nt], 16); s1[nt] += __shfl_xor(s1[nt], 32);
        s2[nt] += __shfl_xor(s2[nt], 16); s2[nt] += __shfl_xor(s2[nt], 32);
        if (quad == 0) {
            atomicAdd(&psum[nt * 16 + col], s1[nt]);
            atomicAdd(&psq[nt * 16 + col], s2[nt]);
        }
    }
    // ---- h2 global store: coalesced uint4 rows from LDS ----
#pragma unroll
    for (int r = 0; r < 4; r++) {
        int lin = lane + 64 * r;
        int row = lin >> 3, c = lin & 7;
        uint4 v = *(const uint4*)&h1s[wv][row][c * 8];
        *(uint4*)&h2[((size_t)g * NS + row) * 64 + c * 8] = v;
    }
    __syncthreads();
    if (t < 64) {
        int slot = blockIdx.x & 63;
        atomicAdd(&stage2[slot * 128 + t], (double)psum[t]);
        atomicAdd(&stage2[slot * 128 + 64 + t], (double)psq[t]);
    }
}

// =====================================================================
// K7: layer3 MFMA (64->128): h3 = h2n @ w2^T + b2. 2mt x 8nt x 2ks =
// 32 MFMA/wave. Emits BN3 partial sums + per-(g,o3) max/min of h3
// (BN3+relu is monotone per sign of a3 -> no 2nd GEMM pass needed).
// =====================================================================
__global__ __launch_bounds__(256) void layer3_kernel(const unsigned short* __restrict__ h2,
                                                     const float* __restrict__ AB2,
                                                     const float* __restrict__ w2,
                                                     const float* __restrict__ b2,
                                                     double* __restrict__ stage3,
                                                     float* __restrict__ mxbuf,
                                                     float* __restrict__ mnbuf) {
    __shared__ __attribute__((aligned(16))) unsigned short w2s[128][72];    // [o3][o2]
    __shared__ __attribute__((aligned(16))) unsigned short h2s[4][32][72];  // [wv][k][o2]
    __shared__ float psum[128], psq[128];
    int t = threadIdx.x, wv = t >> 6, lane = t & 63;
    int quad = lane >> 4, col = lane & 15;
    int g = blockIdx.x * 4 + wv;
    for (int lin = t; lin < 8192; lin += 256)
        w2s[lin >> 6][lin & 63] = f2bf(w2[lin]);
    if (t < 128) { psum[t] = 0.f; psq[t] = 0.f; }
    {   // phase1: h2 -> BN2+relu -> LDS bf16. lane owns channels c*8..c*8+7
        int c = lane & 7;
        float a2v[8], bb2v[8];
#pragma unroll
        for (int j = 0; j < 8; j++) {
            a2v[j] = AB2[c * 8 + j];
            bb2v[j] = AB2[64 + c * 8 + j];
        }
        const unsigned short* hg = h2 + (size_t)g * NS * 64;
#pragma unroll
        for (int r = 0; r < 4; r++) {
            int row = (lane >> 3) + 8 * r;
            union { uint4 v; unsigned short u[8]; } in, outp;
            in.v = *(const uint4*)&hg[row * 64 + c * 8];
#pragma unroll
            for (int j = 0; j < 8; j++) {
                float f = bf2f(in.u[j]);
                outp.u[j] = f2bf(fmaxf(fmaf(f, a2v[j], bb2v[j]), 0.f));
            }
            *(uint4*)&h2s[wv][row][c * 8] = outp.v;
        }
    }
    __syncthreads();
    // ---- MFMA: 2 mt x 8 nt x 2 ks ----
    f32x4 acc[2][8];
#pragma unroll
    for (int i = 0; i < 2; i++)
#pragma unroll
        for (int j = 0; j < 8; j++) acc[i][j] = (f32x4){0.f, 0.f, 0.f, 0.f};
#pragma unroll
    for (int ks = 0; ks < 2; ks++) {
        bf16x8 a0 = as_bf(*(const uint4*)&h2s[wv][col][ks * 32 + quad * 8]);
        bf16x8 a1f = as_bf(*(const uint4*)&h2s[wv][16 + col][ks * 32 + quad * 8]);
#pragma unroll
        for (int nt = 0; nt < 8; nt++) {
            bf16x8 bf = as_bf(*(const uint4*)&w2s[nt * 16 + col][ks * 32 + quad * 8]);
            acc[0][nt] = __builtin_amdgcn_mfma_f32_16x16x32_bf16(a0, bf, acc[0][nt], 0, 0, 0);
            acc[1][nt] = __builtin_amdgcn_mfma_f32_16x16x32_bf16(a1f, bf, acc[1][nt], 0, 0, 0);
        }
    }
    // ---- epilogue: + b2, BN3 stats + per-o3 max/min over k ----
#pragma unroll
    for (int nt = 0; nt < 8; nt++) {
        float bb = b2[nt * 16 + col];
        float s1 = 0.f, s2 = 0.f, mx = -1e30f, mn = 1e30f;
#pragma unroll
        for (int mt = 0; mt < 2; mt++)
#pragma unroll
            for (int r = 0; r < 4; r++) {
                float v = acc[mt][nt][r] + bb;
                s1 += v; s2 = fmaf(v, v, s2);
                mx = fmaxf(mx, v); mn = fminf(mn, v);
            }
        s1 += __shfl_xor(s1, 16); s1 += __shfl_xor(s1, 32);
        s2 += __shfl_xor(s2, 16); s2 += __shfl_xor(s2, 32);
        mx = fmaxf(mx, __shfl_xor(mx, 16)); mx = fmaxf(mx, __shfl_xor(mx, 32));
        mn = fminf(mn, __shfl_xor(mn, 16)); mn = fminf(mn, __shfl_xor(mn, 32));
        if (quad == 0) {
            atomicAdd(&psum[nt * 16 + col], s1);
            atomicAdd(&psq[nt * 16 + col], s2);
            mxbuf[(size_t)g * 128 + nt * 16 + col] = mx;
            mnbuf[(size_t)g * 128 + nt * 16 + col] = mn;
        }
    }
    __syncthreads();
    if (t < 128) {
        int slot = blockIdx.x & 63;
        atomicAdd(&stage3[slot * 256 + t], (double)psum[t]);
        atomicAdd(&stage3[slot * 256 + 128 + t], (double)psq[t]);
    }
}

// =====================================================================
// K9: epilogue. out1[b][o][s] = relu(a3*sel+b3), sel = a3>=0?max:min.
// Coalesced read [s][o] -> LDS -> coalesced transposed write [o][s].
// =====================================================================
__global__ __launch_bounds__(256) void epilogue_kernel(const float* __restrict__ mxbuf,
                                                       const float* __restrict__ mnbuf,
                                                       const float* __restrict__ AB3,
                                                       float* __restrict__ out1) {
    __shared__ float tile[32][65];
    int blk = blockIdx.x;
    int b = blk >> 6; int rem = blk & 63;
    int o0 = (rem >> 4) * 32; int s0 = (rem & 15) * 64;
    int t = threadIdx.x;
#pragma unroll
    for (int j = 0; j < 8; j++) {
        int lin = t + 256 * j;
        int sl = lin >> 5, ol = lin & 31;
        int o = o0 + ol;
        float a = AB3[o], bb = AB3[128 + o];
        size_t src = ((size_t)b * NP + s0 + sl) * 128 + o;
        float v = (a >= 0.f) ? mxbuf[src] : mnbuf[src];
        tile[ol][sl] = fmaxf(fmaf(v, a, bb), 0.f);
    }
    __syncthreads();
#pragma unroll
    for (int j = 0; j < 8; j++) {
        int lin = t + 256 * j;
        int ol = lin >> 6, sl = lin & 63;
        out1[((size_t)b * 128 + o0 + ol) * NP + s0 + sl] = tile[ol][sl];
    }
}

// =====================================================================
extern "C" void kernel_launch(void* const* d_in, const int* in_sizes, int n_in,
                              void* d_out, int out_size, void* d_ws, size_t ws_size,
                              hipStream_t stream) {
    const float* xyz    = (const float*)d_in[0];
    const float* points = (const float*)d_in[1];
    const float* w0  = (const float*)d_in[2];
    const float* b0  = (const float*)d_in[3];
    const float* g0  = (const float*)d_in[4];
    const float* bt0 = (const float*)d_in[5];
    const float* w1  = (const float*)d_in[6];
    const float* b1  = (const float*)d_in[7];
    const float* g1  = (const float*)d_in[8];
    const float* bt1 = (const float*)d_in[9];
    const float* w2  = (const float*)d_in[10];
    const float* b2  = (const float*)d_in[11];
    const float* g2  = (const float*)d_in[12];
    const float* bt2 = (const float*)d_in[13];

    char* ws = (char*)d_ws;
    // workspace layout (bytes, 256-aligned): total ~94.7 MB
    int*            fidx = (int*)(ws + 0);                       //   64 KB
    int*            idx  = (int*)(ws + 65536);                   //    2 MB
    unsigned short* T    = (unsigned short*)(ws + 2162688);      //  8.4 MB bf16
    unsigned short* h2   = (unsigned short*)(ws + 10551296);     //   67 MB bf16
    float*          mxbuf = (float*)(ws + 77660160);             //  8.4 MB
    float*          mnbuf = (float*)(ws + 86048768);             //  8.4 MB
    double*         stage = (double*)(ws + 94437376);            //  256 KB
    float*          AB   = (float*)(ws + 94699520);              //    2 KB (320 floats used)
    int*            sync_ctr = (int*)(ws + 94701312);            // tail of AB's 2KB slot
    double* stage1 = stage;
    double* stage2 = stage + 64 * 128;
    double* stage3 = stage + 2 * 64 * 128;
    float* AB1 = AB; float* AB2 = AB + 128; float* AB3 = AB + 256;
    float* out0 = (float*)d_out;
    float* out1 = out0 + NB * 3 * NP;

    hipMemsetAsync(stage, 0, 262144, stream);        // zero stat slots
    hipMemsetAsync(fidx, 0xFF, NB * NP * 4, stream); // fidx = -1 (spin flags)
    hipMemsetAsync(sync_ctr, 0, 4, stream);          // worker barrier ctr

    fused_kernel<<<256, 256, 0, stream>>>(xyz, points, w0, b0, fidx, T, idx,
                                          stage1, out0, sync_ctr);
    finalize_kernel<<<1, 64, 0, stream>>>(stage1, 64, g0, bt0, AB1);
    layer2_kernel<<<NGRP / 4, 256, 0, stream>>>(xyz, T, fidx, idx, w0, b0, AB1,
                                                w1, b1, h2, stage2);
    finalize_kernel<<<1, 64, 0, stream>>>(stage2, 64, g1, bt1, AB2);
    layer3_kernel<<<NGRP / 4, 256, 0, stream>>>(h2, AB2, w2, b2, stage3, mxbuf, mnbuf);
    finalize_kernel<<<1, 128, 0, stream>>>(stage3, 128, g2, bt2, AB3);
    epilogue_kernel<<<1024, 256, 0, stream>>>(mxbuf, mnbuf, AB3, out1);
}